// Round 1
// baseline (1684.307 us; speedup 1.0000x reference)
//
#include <hip/hip_runtime.h>
#include <hip/hip_bf16.h>
#include <math.h>

// Problem constants
#define NROI   512
#define CCH    256
#define POOLP  7
#define DDIM   12544   // 256*7*7
#define HIDN   1024
#define NCLS   81
#define NREG   324
#define OUT_ROIS   2560           // 2*256*5
#define OUT_CLS    (512*81)       // 41472
#define OUT_REG    (512*324)      // 165888

// ---------------------------------------------------------------------------
// copy rois -> out[0:2560]
__global__ void copy_rois_k(const float* __restrict__ rois, float* __restrict__ out) {
    int i = blockIdx.x * 256 + threadIdx.x;
    if (i < OUT_ROIS) out[i] = rois[i];
}

// ---------------------------------------------------------------------------
// NCHW -> NHWC transpose per level: in (2,256,S) -> out (2,S,256)
__global__ __launch_bounds__(256) void transpose_cs_k(const float* __restrict__ in,
                                                      float* __restrict__ out, int S) {
    __shared__ float tile[32][33];
    int b  = blockIdx.z;
    int s0 = blockIdx.x * 32, c0 = blockIdx.y * 32;
    int s  = s0 + threadIdx.x;
#pragma unroll
    for (int j = 0; j < 32; j += 8) {
        int c = c0 + threadIdx.y + j;
        tile[threadIdx.y + j][threadIdx.x] = (s < S) ? in[((size_t)b * CCH + c) * S + s] : 0.f;
    }
    __syncthreads();
    int c = c0 + threadIdx.x;
#pragma unroll
    for (int j = 0; j < 32; j += 8) {
        int s2 = s0 + threadIdx.y + j;
        if (s2 < S) out[((size_t)b * S + s2) * CCH + c] = tile[threadIdx.x][threadIdx.y + j];
    }
}

// ---------------------------------------------------------------------------
// ROI Align (torchvision-legacy, aligned=false), level select, 2x2 sampling.
// One block per roi, 256 threads = 256 channels. Output x[roi][c*49+py*7+px].
template <bool NHWC>
__global__ __launch_bounds__(256) void roi_align_k(const float* __restrict__ f0,
                                                   const float* __restrict__ f1,
                                                   const float* __restrict__ f2,
                                                   const float* __restrict__ f3,
                                                   const float* __restrict__ rois,
                                                   float* __restrict__ xpool) {
    __shared__ float xs[DDIM];          // 50176 B staging for coalesced write
    __shared__ float s_f[28];
    __shared__ int   s_lo[28], s_hi[28], s_v[28];

    int r = blockIdx.x;
    float r0  = rois[r * 5 + 0];
    float rx1 = rois[r * 5 + 1], ry1 = rois[r * 5 + 2];
    float rx2 = rois[r * 5 + 3], ry2 = rois[r * 5 + 4];
    int b = (int)r0;

    float aw = rx2 - rx1 + 1.f, ah = ry2 - ry1 + 1.f;
    float lvf = floorf(log2f(sqrtf(ah * aw) / 56.f + 1e-6f));
    int lv = (int)fminf(fmaxf(lvf, 0.f), 3.f);

    const float* F = (lv == 0) ? f0 : (lv == 1) ? f1 : (lv == 2) ? f2 : f3;
    int HW      = (lv == 0) ? 200 : (lv == 1) ? 100 : (lv == 2) ? 50 : 25;
    float scale = (lv == 0) ? 0.25f : (lv == 1) ? 0.125f : (lv == 2) ? 0.0625f : 0.03125f;

    float x1 = rx1 * scale, yy1 = ry1 * scale;
    float x2 = rx2 * scale, yy2 = ry2 * scale;
    float rw = fmaxf(x2 - x1, 1.f), rh = fmaxf(yy2 - yy1, 1.f);

    int t = threadIdx.x;
    if (t < 28) {
        bool isY = t < 14;
        int  i   = isY ? t : t - 14;
        // g = p + (s+0.5)/2, i = p*2+s
        float g = (float)(i >> 1) + ((float)(i & 1) + 0.5f) * 0.5f;
        float coord = isY ? (yy1 + g * (rh * (1.f / 7.f)))
                          : (x1 + g * (rw * (1.f / 7.f)));
        int vld = (coord >= -1.f && coord <= (float)HW) ? 1 : 0;
        float c = fminf(fmaxf(coord, 0.f), (float)(HW - 1));
        int lo  = (int)floorf(c);
        int hi  = min(lo + 1, HW - 1);
        s_v[t] = vld; s_lo[t] = lo; s_hi[t] = hi; s_f[t] = c - (float)lo;
    }
    __syncthreads();

    int    cch = t;
    size_t S   = (size_t)HW * HW;
    const float* Fb = NHWC ? (F + (size_t)b * S * CCH + cch)
                           : (F + ((size_t)b * CCH + cch) * S);

    for (int py = 0; py < POOLP; py++) {
        for (int px = 0; px < POOLP; px++) {
            float acc = 0.f;
#pragma unroll
            for (int s = 0; s < 4; s++) {
                int iy = py * 2 + (s >> 1);
                int ix = px * 2 + (s & 1);
                int vy = s_v[iy], vx = s_v[14 + ix];
                if (vy & vx) {
                    float fy = s_f[iy], fx = s_f[14 + ix];
                    int ylo = s_lo[iy], yhi = s_hi[iy];
                    int xlo = s_lo[14 + ix], xhi = s_hi[14 + ix];
                    float v00, v01, v10, v11;
                    if (NHWC) {
                        v00 = Fb[((size_t)ylo * HW + xlo) * CCH];
                        v01 = Fb[((size_t)ylo * HW + xhi) * CCH];
                        v10 = Fb[((size_t)yhi * HW + xlo) * CCH];
                        v11 = Fb[((size_t)yhi * HW + xhi) * CCH];
                    } else {
                        v00 = Fb[(size_t)ylo * HW + xlo];
                        v01 = Fb[(size_t)ylo * HW + xhi];
                        v10 = Fb[(size_t)yhi * HW + xlo];
                        v11 = Fb[(size_t)yhi * HW + xhi];
                    }
                    acc += (1.f - fy) * ((1.f - fx) * v00 + fx * v01)
                         + fy * ((1.f - fx) * v10 + fx * v11);
                }
            }
            xs[cch * 49 + py * 7 + px] = acc * 0.25f;
        }
    }
    __syncthreads();
    size_t base = (size_t)r * DDIM;
    for (int k = t; k < DDIM; k += 256) xpool[base + k] = xs[k];
}

// ---------------------------------------------------------------------------
// fp32 GEMM: C(M,N) = op(A(M,K) * Bw(N,K)^T + bias). ACT=1 -> relu.
// BM=32, BN=64, BK=16, 256 threads, 2x4 micro-tile. M%32==0, K%16==0 assumed.
template <int ACT>
__global__ __launch_bounds__(256) void gemm_nt_k(const float* __restrict__ A,
                                                 const float* __restrict__ Bw,
                                                 const float* __restrict__ bias,
                                                 float* __restrict__ C,
                                                 int M, int N, int K) {
    __shared__ __align__(16) float As[16][34];
    __shared__ __align__(16) float Bs[16][68];

    int t  = threadIdx.x;
    int m0 = blockIdx.y * 32, n0 = blockIdx.x * 64;
    int tm = t & 15, tn = t >> 4;
    int kq = t & 15, rr = t >> 4;

    float acc[2][4] = {};

    for (int k0 = 0; k0 < K; k0 += 16) {
#pragma unroll
        for (int i = 0; i < 2; i++) {
            int m = rr + i * 16;
            As[kq][m] = A[(size_t)(m0 + m) * K + k0 + kq];
        }
#pragma unroll
        for (int i = 0; i < 4; i++) {
            int n = rr + i * 16;
            Bs[kq][n] = (n0 + n < N) ? Bw[(size_t)(n0 + n) * K + k0 + kq] : 0.f;
        }
        __syncthreads();
#pragma unroll
        for (int k = 0; k < 16; k++) {
            float2 a  = *(const float2*)&As[k][tm * 2];
            float4 bv = *(const float4*)&Bs[k][tn * 4];
            acc[0][0] += a.x * bv.x; acc[0][1] += a.x * bv.y;
            acc[0][2] += a.x * bv.z; acc[0][3] += a.x * bv.w;
            acc[1][0] += a.y * bv.x; acc[1][1] += a.y * bv.y;
            acc[1][2] += a.y * bv.z; acc[1][3] += a.y * bv.w;
        }
        __syncthreads();
    }

#pragma unroll
    for (int i = 0; i < 2; i++) {
#pragma unroll
        for (int j = 0; j < 4; j++) {
            int m = m0 + tm * 2 + i;
            int n = n0 + tn * 4 + j;
            if (n < N) {
                float v = acc[i][j] + bias[n];
                if (ACT) v = fmaxf(v, 0.f);
                C[(size_t)m * N + n] = v;
            }
        }
    }
}

// ---------------------------------------------------------------------------
// softmax over 81 classes per roi; one wave per row.
__global__ void softmax81_k(const float* __restrict__ logits, float* __restrict__ out) {
    int r = blockIdx.x;
    int l = threadIdx.x;  // 0..63
    float v0 = logits[r * NCLS + l];                                  // l < 64 < 81
    float v1 = (l + 64 < NCLS) ? logits[r * NCLS + l + 64] : -INFINITY;
    float m = fmaxf(v0, v1);
#pragma unroll
    for (int o = 32; o; o >>= 1) m = fmaxf(m, __shfl_xor(m, o));
    float e0 = __expf(v0 - m);
    float e1 = (l + 64 < NCLS) ? __expf(v1 - m) : 0.f;
    float s = e0 + e1;
#pragma unroll
    for (int o = 32; o; o >>= 1) s += __shfl_xor(s, o);
    float inv = 1.f / s;
    out[r * NCLS + l] = e0 * inv;
    if (l + 64 < NCLS) out[r * NCLS + l + 64] = e1 * inv;
}

// ---------------------------------------------------------------------------
extern "C" void kernel_launch(void* const* d_in, const int* in_sizes, int n_in,
                              void* d_out, int out_size, void* d_ws, size_t ws_size,
                              hipStream_t stream) {
    const float* p2   = (const float*)d_in[0];
    const float* p3   = (const float*)d_in[1];
    const float* p4   = (const float*)d_in[2];
    const float* p5   = (const float*)d_in[3];
    const float* rois = (const float*)d_in[4];
    const float* w1   = (const float*)d_in[5];
    const float* b1   = (const float*)d_in[6];
    const float* w2   = (const float*)d_in[7];
    const float* b2   = (const float*)d_in[8];
    const float* wc   = (const float*)d_in[9];
    const float* bc   = (const float*)d_in[10];
    const float* wr   = (const float*)d_in[11];
    const float* br   = (const float*)d_in[12];

    float* out = (float*)d_out;
    float* ws  = (float*)d_ws;

    // workspace layout (floats)
    float* xpool  = ws;                                  // 512*12544
    float* y1     = xpool + (size_t)NROI * DDIM;         // 512*1024
    float* y2     = y1 + (size_t)NROI * HIDN;            // 512*1024
    float* logits = y2 + (size_t)NROI * HIDN;            // 512*81
    float* ft0    = logits + (size_t)NROI * NCLS;        // 2*40000*256
    float* ft1    = ft0 + (size_t)2 * 40000 * CCH;       // 2*10000*256
    float* ft2    = ft1 + (size_t)2 * 10000 * CCH;       // 2*2500*256
    float* ft3    = ft2 + (size_t)2 * 2500 * CCH;        // 2*625*256
    size_t nhwc_floats = (size_t)(ft3 - ws) + (size_t)2 * 625 * CCH;
    bool   nhwc = ws_size >= nhwc_floats * sizeof(float);

    copy_rois_k<<<(OUT_ROIS + 255) / 256, 256, 0, stream>>>(rois, out);

    if (nhwc) {
        dim3 blk(32, 8);
        transpose_cs_k<<<dim3(1250, 8, 2), blk, 0, stream>>>(p2, ft0, 40000);
        transpose_cs_k<<<dim3(313, 8, 2),  blk, 0, stream>>>(p3, ft1, 10000);
        transpose_cs_k<<<dim3(79, 8, 2),   blk, 0, stream>>>(p4, ft2, 2500);
        transpose_cs_k<<<dim3(20, 8, 2),   blk, 0, stream>>>(p5, ft3, 625);
        roi_align_k<true><<<NROI, 256, 0, stream>>>(ft0, ft1, ft2, ft3, rois, xpool);
    } else {
        roi_align_k<false><<<NROI, 256, 0, stream>>>(p2, p3, p4, p5, rois, xpool);
    }

    // FC1 + relu: (512,12544) x (1024,12544)^T
    gemm_nt_k<1><<<dim3(16, 16), 256, 0, stream>>>(xpool, w1, b1, y1, NROI, HIDN, DDIM);
    // FC2 + relu
    gemm_nt_k<1><<<dim3(16, 16), 256, 0, stream>>>(y1, w2, b2, y2, NROI, HIDN, HIDN);
    // cls logits -> ws
    gemm_nt_k<0><<<dim3(2, 16), 256, 0, stream>>>(y2, wc, bc, logits, NROI, NCLS, HIDN);
    // bbox preds -> out directly
    gemm_nt_k<0><<<dim3(6, 16), 256, 0, stream>>>(y2, wr, br, out + OUT_ROIS + OUT_CLS,
                                                  NROI, NREG, HIDN);
    // softmax -> out
    softmax81_k<<<NROI, 64, 0, stream>>>(logits, out + OUT_ROIS);
}

// Round 2
// 246.321 us; speedup vs baseline: 6.8379x; 6.8379x over previous
//
#include <hip/hip_runtime.h>
#include <hip/hip_bf16.h>
#include <math.h>

// Problem constants
#define NROI   512
#define CCH    256
#define POOLP  7
#define DDIM   12544   // 256*7*7
#define HIDN   1024
#define NCLS   81
#define NREG   324
#define NHEAD  512           // padded head N: 81 cls + 324 reg + 107 pad
#define OUT_ROIS   2560      // 2*256*5
#define OUT_CLS    (512*81)

typedef __attribute__((ext_vector_type(4))) float f32x4;
typedef __attribute__((ext_vector_type(8))) short bf16x8;

static __device__ __forceinline__ unsigned short f2bf(float x) {
    __hip_bfloat16 h = __float2bfloat16(x);
    return *reinterpret_cast<unsigned short*>(&h);
}

// ---------------------------------------------------------------------------
__global__ void copy_rois_k(const float* __restrict__ rois, float* __restrict__ out) {
    int i = blockIdx.x * 256 + threadIdx.x;
    if (i < OUT_ROIS) out[i] = rois[i];
}

// ---------------------------------------------------------------------------
// fp32 -> bf16 convert, 4 elems/thread
__global__ __launch_bounds__(256) void cvt_bf16_k(const float4* __restrict__ in,
                                                  ushort4* __restrict__ out, int n4) {
    int i = blockIdx.x * 256 + threadIdx.x;
    if (i >= n4) return;
    float4 v = in[i];
    ushort4 o;
    o.x = f2bf(v.x); o.y = f2bf(v.y); o.z = f2bf(v.z); o.w = f2bf(v.w);
    out[i] = o;
}

// pack cls+reg weights into padded (512,1024) bf16
__global__ __launch_bounds__(256) void pack_head_k(const float* __restrict__ wc,
                                                   const float* __restrict__ wr,
                                                   unsigned short* __restrict__ Wh) {
    int i = blockIdx.x * 256 + threadIdx.x;   // 512*1024
    int r = i >> 10, c = i & 1023;
    float v = (r < NCLS) ? wc[r * HIDN + c]
            : (r < NCLS + NREG) ? wr[(r - NCLS) * HIDN + c] : 0.f;
    Wh[i] = f2bf(v);
}

// ---------------------------------------------------------------------------
// NCHW -> NHWC transpose per level: in (2,256,S) -> out (2,S,256)
__global__ __launch_bounds__(256) void transpose_cs_k(const float* __restrict__ in,
                                                      float* __restrict__ out, int S) {
    __shared__ float tile[32][33];
    int b  = blockIdx.z;
    int s0 = blockIdx.x * 32, c0 = blockIdx.y * 32;
    int s  = s0 + threadIdx.x;
#pragma unroll
    for (int j = 0; j < 32; j += 8) {
        int c = c0 + threadIdx.y + j;
        tile[threadIdx.y + j][threadIdx.x] = (s < S) ? in[((size_t)b * CCH + c) * S + s] : 0.f;
    }
    __syncthreads();
    int c = c0 + threadIdx.x;
#pragma unroll
    for (int j = 0; j < 32; j += 8) {
        int s2 = s0 + threadIdx.y + j;
        if (s2 < S) out[((size_t)b * S + s2) * CCH + c] = tile[threadIdx.x][threadIdx.y + j];
    }
}

// ---------------------------------------------------------------------------
// ROI Align -> bf16 xpool [512][12544]
template <bool NHWC>
__global__ __launch_bounds__(256) void roi_align_k(const float* __restrict__ f0,
                                                   const float* __restrict__ f1,
                                                   const float* __restrict__ f2,
                                                   const float* __restrict__ f3,
                                                   const float* __restrict__ rois,
                                                   unsigned short* __restrict__ xpool) {
    __shared__ float xs[DDIM];
    __shared__ float s_f[28];
    __shared__ int   s_lo[28], s_hi[28], s_v[28];

    int r = blockIdx.x;
    float r0  = rois[r * 5 + 0];
    float rx1 = rois[r * 5 + 1], ry1 = rois[r * 5 + 2];
    float rx2 = rois[r * 5 + 3], ry2 = rois[r * 5 + 4];
    int b = (int)r0;

    float aw = rx2 - rx1 + 1.f, ah = ry2 - ry1 + 1.f;
    float lvf = floorf(log2f(sqrtf(ah * aw) / 56.f + 1e-6f));
    int lv = (int)fminf(fmaxf(lvf, 0.f), 3.f);

    const float* F = (lv == 0) ? f0 : (lv == 1) ? f1 : (lv == 2) ? f2 : f3;
    int HW      = (lv == 0) ? 200 : (lv == 1) ? 100 : (lv == 2) ? 50 : 25;
    float scale = (lv == 0) ? 0.25f : (lv == 1) ? 0.125f : (lv == 2) ? 0.0625f : 0.03125f;

    float x1 = rx1 * scale, yy1 = ry1 * scale;
    float x2 = rx2 * scale, yy2 = ry2 * scale;
    float rw = fmaxf(x2 - x1, 1.f), rh = fmaxf(yy2 - yy1, 1.f);

    int t = threadIdx.x;
    if (t < 28) {
        bool isY = t < 14;
        int  i   = isY ? t : t - 14;
        float g = (float)(i >> 1) + ((float)(i & 1) + 0.5f) * 0.5f;
        float coord = isY ? (yy1 + g * (rh * (1.f / 7.f)))
                          : (x1 + g * (rw * (1.f / 7.f)));
        int vld = (coord >= -1.f && coord <= (float)HW) ? 1 : 0;
        float c = fminf(fmaxf(coord, 0.f), (float)(HW - 1));
        int lo  = (int)floorf(c);
        int hi  = min(lo + 1, HW - 1);
        s_v[t] = vld; s_lo[t] = lo; s_hi[t] = hi; s_f[t] = c - (float)lo;
    }
    __syncthreads();

    int    cch = t;
    size_t S   = (size_t)HW * HW;
    const float* Fb = NHWC ? (F + (size_t)b * S * CCH + cch)
                           : (F + ((size_t)b * CCH + cch) * S);

    for (int py = 0; py < POOLP; py++) {
        for (int px = 0; px < POOLP; px++) {
            float acc = 0.f;
#pragma unroll
            for (int s = 0; s < 4; s++) {
                int iy = py * 2 + (s >> 1);
                int ix = px * 2 + (s & 1);
                int vy = s_v[iy], vx = s_v[14 + ix];
                if (vy & vx) {
                    float fy = s_f[iy], fx = s_f[14 + ix];
                    int ylo = s_lo[iy], yhi = s_hi[iy];
                    int xlo = s_lo[14 + ix], xhi = s_hi[14 + ix];
                    float v00, v01, v10, v11;
                    if (NHWC) {
                        v00 = Fb[((size_t)ylo * HW + xlo) * CCH];
                        v01 = Fb[((size_t)ylo * HW + xhi) * CCH];
                        v10 = Fb[((size_t)yhi * HW + xlo) * CCH];
                        v11 = Fb[((size_t)yhi * HW + xhi) * CCH];
                    } else {
                        v00 = Fb[(size_t)ylo * HW + xlo];
                        v01 = Fb[(size_t)ylo * HW + xhi];
                        v10 = Fb[(size_t)yhi * HW + xlo];
                        v11 = Fb[(size_t)yhi * HW + xhi];
                    }
                    acc += (1.f - fy) * ((1.f - fx) * v00 + fx * v01)
                         + fy * ((1.f - fx) * v10 + fx * v11);
                }
            }
            xs[cch * 49 + py * 7 + px] = acc * 0.25f;
        }
    }
    __syncthreads();
    size_t base = (size_t)r * DDIM;
    for (int k = t; k < DDIM; k += 256) xpool[base + k] = f2bf(xs[k]);
}

// ---------------------------------------------------------------------------
// bf16 MFMA GEMM with split-K partials.
// C_partial[z] (M,N) = A(M,K[chunk z]) * W(N,K[chunk z])^T
// BM=BN=64, BK=64, 256 threads = 4 waves in 2x2, each wave 32x32 out.
// LDS layout [kgroup][row][8] -> conflict-minimal ds_read_b128 frag loads,
// staged via global_load_lds width=16 (wave-uniform LDS base, per-lane gsrc).
// M,N multiples of 64; kchunk multiple of 64.
__global__ __launch_bounds__(256) void gemm_bf16_k(const unsigned short* __restrict__ A,
                                                   const unsigned short* __restrict__ W,
                                                   float* __restrict__ Cp,
                                                   int M, int N, int K, int kchunk) {
    __shared__ __align__(16) unsigned short As[8][64][8];
    __shared__ __align__(16) unsigned short Ws[8][64][8];

    int t = threadIdx.x;
    int lane = t & 63, wid = t >> 6;
    int m0 = blockIdx.y * 64, n0 = blockIdx.x * 64;
    int k0 = blockIdx.z * kchunk;
    int wm = (wid >> 1) * 32, wn = (wid & 1) * 32;
    int fr = lane & 15, kg = lane >> 4;

    f32x4 acc[2][2] = {};

    const unsigned short* Arow = A + (size_t)(m0 + lane) * K;
    const unsigned short* Wrow = W + (size_t)(n0 + lane) * K;

    for (int kb = k0; kb < k0 + kchunk; kb += 64) {
#pragma unroll
        for (int i = 0; i < 2; i++) {
            int c = wid * 2 + i;   // wave-uniform chunk id 0..7
            __builtin_amdgcn_global_load_lds(
                (const __attribute__((address_space(1))) void*)(Arow + kb + c * 8),
                (__attribute__((address_space(3))) void*)(&As[c][0][0]), 16, 0, 0);
            __builtin_amdgcn_global_load_lds(
                (const __attribute__((address_space(1))) void*)(Wrow + kb + c * 8),
                (__attribute__((address_space(3))) void*)(&Ws[c][0][0]), 16, 0, 0);
        }
        __syncthreads();
#pragma unroll
        for (int h = 0; h < 2; h++) {
            bf16x8 a0 = *(const bf16x8*)(&As[h * 4 + kg][wm + fr][0]);
            bf16x8 a1 = *(const bf16x8*)(&As[h * 4 + kg][wm + 16 + fr][0]);
            bf16x8 b0 = *(const bf16x8*)(&Ws[h * 4 + kg][wn + fr][0]);
            bf16x8 b1 = *(const bf16x8*)(&Ws[h * 4 + kg][wn + 16 + fr][0]);
            acc[0][0] = __builtin_amdgcn_mfma_f32_16x16x32_bf16(a0, b0, acc[0][0], 0, 0, 0);
            acc[0][1] = __builtin_amdgcn_mfma_f32_16x16x32_bf16(a0, b1, acc[0][1], 0, 0, 0);
            acc[1][0] = __builtin_amdgcn_mfma_f32_16x16x32_bf16(a1, b0, acc[1][0], 0, 0, 0);
            acc[1][1] = __builtin_amdgcn_mfma_f32_16x16x32_bf16(a1, b1, acc[1][1], 0, 0, 0);
        }
        __syncthreads();
    }

    float* Cout = Cp + (size_t)blockIdx.z * M * N;
    int row = m0 + wm + (lane >> 4) * 4;
    int col = n0 + wn + (lane & 15);
#pragma unroll
    for (int fm = 0; fm < 2; fm++)
#pragma unroll
        for (int fn = 0; fn < 2; fn++)
#pragma unroll
            for (int r = 0; r < 4; r++)
                Cout[(size_t)(row + fm * 16 + r) * N + col + fn * 16] = acc[fm][fn][r];
}

// ---------------------------------------------------------------------------
// sum split-K partials + bias + relu -> bf16 (N == HIDN, power of 2)
__global__ __launch_bounds__(256) void reduce_relu_k(const float* __restrict__ Cp,
                                                     const float* __restrict__ bias,
                                                     unsigned short* __restrict__ out,
                                                     int MN, int ks) {
    int i = blockIdx.x * 256 + threadIdx.x;
    if (i >= MN) return;
    float s = 0.f;
    for (int p = 0; p < ks; p++) s += Cp[(size_t)p * MN + i];
    s = fmaxf(s + bias[i & (HIDN - 1)], 0.f);
    out[i] = f2bf(s);
}

// head partials (512 x 512 padded) -> cls logits (ws) + reg preds (out)
__global__ __launch_bounds__(256) void head_reduce_k(const float* __restrict__ Cp,
                                                     const float* __restrict__ bc,
                                                     const float* __restrict__ br,
                                                     float* __restrict__ cls_logits,
                                                     float* __restrict__ reg_out, int ks) {
    int i = blockIdx.x * 256 + threadIdx.x;   // 512*512
    int r = i >> 9, c = i & 511;
    float s = 0.f;
    for (int p = 0; p < ks; p++) s += Cp[(size_t)p * (512 * 512) + i];
    if (c < NCLS) cls_logits[r * NCLS + c] = s + bc[c];
    else if (c < NCLS + NREG) reg_out[r * NREG + (c - NCLS)] = s + br[c - NCLS];
}

// ---------------------------------------------------------------------------
__global__ void softmax81_k(const float* __restrict__ logits, float* __restrict__ out) {
    int r = blockIdx.x;
    int l = threadIdx.x;  // 0..63
    float v0 = logits[r * NCLS + l];
    float v1 = (l + 64 < NCLS) ? logits[r * NCLS + l + 64] : -INFINITY;
    float m = fmaxf(v0, v1);
#pragma unroll
    for (int o = 32; o; o >>= 1) m = fmaxf(m, __shfl_xor(m, o));
    float e0 = __expf(v0 - m);
    float e1 = (l + 64 < NCLS) ? __expf(v1 - m) : 0.f;
    float s = e0 + e1;
#pragma unroll
    for (int o = 32; o; o >>= 1) s += __shfl_xor(s, o);
    float inv = 1.f / s;
    out[r * NCLS + l] = e0 * inv;
    if (l + 64 < NCLS) out[r * NCLS + l + 64] = e1 * inv;
}

// ---------------------------------------------------------------------------
extern "C" void kernel_launch(void* const* d_in, const int* in_sizes, int n_in,
                              void* d_out, int out_size, void* d_ws, size_t ws_size,
                              hipStream_t stream) {
    const float* p2   = (const float*)d_in[0];
    const float* p3   = (const float*)d_in[1];
    const float* p4   = (const float*)d_in[2];
    const float* p5   = (const float*)d_in[3];
    const float* rois = (const float*)d_in[4];
    const float* w1   = (const float*)d_in[5];
    const float* b1   = (const float*)d_in[6];
    const float* w2   = (const float*)d_in[7];
    const float* b2   = (const float*)d_in[8];
    const float* wc   = (const float*)d_in[9];
    const float* bc   = (const float*)d_in[10];
    const float* wr   = (const float*)d_in[11];
    const float* br   = (const float*)d_in[12];

    float* out = (float*)d_out;

    // workspace carve-up (256B-aligned chunks)
    char* p = (char*)d_ws;
    auto alloc = [&](size_t bytes) { char* r = p; p += (bytes + 255) & ~(size_t)255; return r; };
    unsigned short* xpool = (unsigned short*)alloc((size_t)NROI * DDIM * 2);   // 12.8 MB
    unsigned short* y1b   = (unsigned short*)alloc((size_t)NROI * HIDN * 2);   // 1 MB
    unsigned short* y2b   = (unsigned short*)alloc((size_t)NROI * HIDN * 2);   // 1 MB
    unsigned short* w1b   = (unsigned short*)alloc((size_t)HIDN * DDIM * 2);   // 25.7 MB
    unsigned short* w2b   = (unsigned short*)alloc((size_t)HIDN * HIDN * 2);   // 2.1 MB
    unsigned short* whd   = (unsigned short*)alloc((size_t)NHEAD * HIDN * 2);  // 1 MB
    float*          clsl  = (float*)alloc((size_t)NROI * NCLS * 4);            // 166 KB
    float*          part  = (float*)alloc((size_t)4 * NROI * HIDN * 4);        // 8 MB
    float* ft0 = (float*)alloc((size_t)2 * 40000 * CCH * 4);
    float* ft1 = (float*)alloc((size_t)2 * 10000 * CCH * 4);
    float* ft2 = (float*)alloc((size_t)2 * 2500 * CCH * 4);
    float* ft3 = (float*)alloc((size_t)2 * 625 * CCH * 4);
    bool nhwc = (size_t)(p - (char*)d_ws) <= ws_size;

    copy_rois_k<<<(OUT_ROIS + 255) / 256, 256, 0, stream>>>(rois, out);

    // weight conversions
    cvt_bf16_k<<<(HIDN * DDIM / 4 + 255) / 256, 256, 0, stream>>>(
        (const float4*)w1, (ushort4*)w1b, HIDN * DDIM / 4);
    cvt_bf16_k<<<(HIDN * HIDN / 4 + 255) / 256, 256, 0, stream>>>(
        (const float4*)w2, (ushort4*)w2b, HIDN * HIDN / 4);
    pack_head_k<<<(NHEAD * HIDN + 255) / 256, 256, 0, stream>>>(wc, wr, whd);

    if (nhwc) {
        dim3 blk(32, 8);
        transpose_cs_k<<<dim3(1250, 8, 2), blk, 0, stream>>>(p2, ft0, 40000);
        transpose_cs_k<<<dim3(313, 8, 2),  blk, 0, stream>>>(p3, ft1, 10000);
        transpose_cs_k<<<dim3(79, 8, 2),   blk, 0, stream>>>(p4, ft2, 2500);
        transpose_cs_k<<<dim3(20, 8, 2),   blk, 0, stream>>>(p5, ft3, 625);
        roi_align_k<true><<<NROI, 256, 0, stream>>>(ft0, ft1, ft2, ft3, rois, xpool);
    } else {
        roi_align_k<false><<<NROI, 256, 0, stream>>>(p2, p3, p4, p5, rois, xpool);
    }

    // FC1: (512,12544)x(1024,12544)^T, split-K 4
    gemm_bf16_k<<<dim3(HIDN / 64, NROI / 64, 4), 256, 0, stream>>>(
        xpool, w1b, part, NROI, HIDN, DDIM, DDIM / 4);
    reduce_relu_k<<<(NROI * HIDN + 255) / 256, 256, 0, stream>>>(
        part, b1, y1b, NROI * HIDN, 4);

    // FC2: (512,1024)x(1024,1024)^T, split-K 2
    gemm_bf16_k<<<dim3(HIDN / 64, NROI / 64, 2), 256, 0, stream>>>(
        y1b, w2b, part, NROI, HIDN, HIDN, HIDN / 2);
    reduce_relu_k<<<(NROI * HIDN + 255) / 256, 256, 0, stream>>>(
        part, b2, y2b, NROI * HIDN, 2);

    // head: (512,1024)x(512,1024)^T, split-K 4
    gemm_bf16_k<<<dim3(NHEAD / 64, NROI / 64, 4), 256, 0, stream>>>(
        y2b, whd, part, NROI, NHEAD, HIDN, HIDN / 4);
    head_reduce_k<<<(NROI * NHEAD + 255) / 256, 256, 0, stream>>>(
        part, bc, br, clsl, out + OUT_ROIS + OUT_CLS, 4);

    softmax81_k<<<NROI, 64, 0, stream>>>(clsl, out + OUT_ROIS);
}

// Round 3
// 172.404 us; speedup vs baseline: 9.7696x; 1.4287x over previous
//
#include <hip/hip_runtime.h>
#include <hip/hip_bf16.h>
#include <math.h>

// Problem constants
#define NROI   512
#define CCH    256
#define POOLP  7
#define DDIM   12544   // 256*7*7
#define HIDN   1024
#define NCLS   81
#define NREG   324
#define NHEAD  512           // padded head N: 81 cls + 324 reg + 107 pad
#define OUT_ROIS   2560      // 2*256*5
#define OUT_CLS    (512*81)

typedef __attribute__((ext_vector_type(4))) float f32x4;
typedef __attribute__((ext_vector_type(8))) short bf16x8;

static __device__ __forceinline__ unsigned short f2bf(float x) {
    __hip_bfloat16 h = __float2bfloat16(x);
    return *reinterpret_cast<unsigned short*>(&h);
}
static __device__ __forceinline__ float bf2f(unsigned short u) {
    unsigned int b = ((unsigned int)u) << 16;
    return *reinterpret_cast<float*>(&b);
}

// ---------------------------------------------------------------------------
__global__ void copy_rois_k(const float* __restrict__ rois, float* __restrict__ out) {
    int i = blockIdx.x * 256 + threadIdx.x;
    if (i < OUT_ROIS) out[i] = rois[i];
}

// ---------------------------------------------------------------------------
// fp32 -> bf16 convert, 4 elems/thread
__global__ __launch_bounds__(256) void cvt_bf16_k(const float4* __restrict__ in,
                                                  ushort4* __restrict__ out, int n4) {
    int i = blockIdx.x * 256 + threadIdx.x;
    if (i >= n4) return;
    float4 v = in[i];
    ushort4 o;
    o.x = f2bf(v.x); o.y = f2bf(v.y); o.z = f2bf(v.z); o.w = f2bf(v.w);
    out[i] = o;
}

// pack cls+reg weights into padded (512,1024) bf16
__global__ __launch_bounds__(256) void pack_head_k(const float* __restrict__ wc,
                                                   const float* __restrict__ wr,
                                                   unsigned short* __restrict__ Wh) {
    int i = blockIdx.x * 256 + threadIdx.x;   // 512*1024
    int r = i >> 10, c = i & 1023;
    float v = (r < NCLS) ? wc[r * HIDN + c]
            : (r < NCLS + NREG) ? wr[(r - NCLS) * HIDN + c] : 0.f;
    Wh[i] = f2bf(v);
}

// w1 column-permute + bf16: w1b[n][s*256+c] = w1[n][c*49+s]  (s=py*7+px)
__global__ __launch_bounds__(256) void permute_w1_k(const float* __restrict__ w1,
                                                    unsigned short* __restrict__ w1b) {
    __shared__ unsigned short lw[49 * 258];   // +2 pad per s-row: conflict-free
    int n = blockIdx.x, t = threadIdx.x;
    const float* src = w1 + (size_t)n * DDIM;
#pragma unroll
    for (int k = t; k < DDIM; k += 256) {
        int c = k / 49;            // compiler magic-mul
        int s = k - c * 49;
        lw[s * 258 + c] = f2bf(src[k]);
    }
    __syncthreads();
    unsigned int* dst = (unsigned int*)(w1b + (size_t)n * DDIM);
    for (int j2 = t; j2 < DDIM / 2; j2 += 256) {
        int s  = j2 >> 7;
        int c2 = (j2 & 127) << 1;
        unsigned int v = lw[s * 258 + c2] | ((unsigned int)lw[s * 258 + c2 + 1] << 16);
        dst[j2] = v;
    }
}

// ---------------------------------------------------------------------------
// NCHW fp32 -> NHWC bf16 transpose per level: in (2,256,S) -> out (2,S,256)
__global__ __launch_bounds__(256) void transpose_cvt_k(const float* __restrict__ in,
                                                       unsigned short* __restrict__ out,
                                                       int S) {
    __shared__ float tile[32][33];
    int b  = blockIdx.z;
    int s0 = blockIdx.x * 32, c0 = blockIdx.y * 32;
    int s  = s0 + threadIdx.x;
#pragma unroll
    for (int j = 0; j < 32; j += 8) {
        int c = c0 + threadIdx.y + j;
        tile[threadIdx.y + j][threadIdx.x] = (s < S) ? in[((size_t)b * CCH + c) * S + s] : 0.f;
    }
    __syncthreads();
    int c = c0 + threadIdx.x;
#pragma unroll
    for (int j = 0; j < 32; j += 8) {
        int s2 = s0 + threadIdx.y + j;
        if (s2 < S) out[((size_t)b * S + s2) * CCH + c] = f2bf(tile[threadIdx.x][threadIdx.y + j]);
    }
}

// ---------------------------------------------------------------------------
// ROI Align, block per (py, roi), 256 threads = channels, bf16 NHWC features.
// xpool[r][ (py*7+px)*256 + c ]  (k-permuted layout, matches permute_w1_k)
__global__ __launch_bounds__(256) void roi_align_k(const unsigned short* __restrict__ f0,
                                                   const unsigned short* __restrict__ f1,
                                                   const unsigned short* __restrict__ f2,
                                                   const unsigned short* __restrict__ f3,
                                                   const float* __restrict__ rois,
                                                   unsigned short* __restrict__ xpool) {
    __shared__ float s_f[16];
    __shared__ int   s_lo[16], s_hi[16], s_v[16];

    int py = blockIdx.x, r = blockIdx.y, t = threadIdx.x;

    float r0  = rois[r * 5 + 0];
    float rx1 = rois[r * 5 + 1], ry1 = rois[r * 5 + 2];
    float rx2 = rois[r * 5 + 3], ry2 = rois[r * 5 + 4];
    int b = (int)r0;

    float aw = rx2 - rx1 + 1.f, ah = ry2 - ry1 + 1.f;
    float lvf = floorf(log2f(sqrtf(ah * aw) / 56.f + 1e-6f));
    int lv = (int)fminf(fmaxf(lvf, 0.f), 3.f);

    const unsigned short* F = (lv == 0) ? f0 : (lv == 1) ? f1 : (lv == 2) ? f2 : f3;
    int HW      = (lv == 0) ? 200 : (lv == 1) ? 100 : (lv == 2) ? 50 : 25;
    float scale = (lv == 0) ? 0.25f : (lv == 1) ? 0.125f : (lv == 2) ? 0.0625f : 0.03125f;

    float x1 = rx1 * scale, yy1 = ry1 * scale;
    float x2 = rx2 * scale, yy2 = ry2 * scale;
    float rw = fmaxf(x2 - x1, 1.f), rh = fmaxf(yy2 - yy1, 1.f);

    if (t < 16) {
        bool isY = t < 2;
        float coord;
        if (isY) {
            float g = (float)py + ((float)t + 0.5f) * 0.5f;
            coord = yy1 + g * (rh * (1.f / 7.f));
        } else {
            int j = t - 2;                    // 0..13
            float g = (float)(j >> 1) + ((float)(j & 1) + 0.5f) * 0.5f;
            coord = x1 + g * (rw * (1.f / 7.f));
        }
        int vld = (coord >= -1.f && coord <= (float)HW) ? 1 : 0;
        float c = fminf(fmaxf(coord, 0.f), (float)(HW - 1));
        int lo  = (int)floorf(c);
        int hi  = min(lo + 1, HW - 1);
        s_v[t] = vld; s_lo[t] = lo; s_hi[t] = hi; s_f[t] = c - (float)lo;
    }
    __syncthreads();

    const unsigned short* Fb = F + ((size_t)b * HW * HW) * CCH + t;
    size_t obase = (size_t)r * DDIM + py * 7 * 256 + t;

    for (int px = 0; px < POOLP; px++) {
        float acc = 0.f;
#pragma unroll
        for (int s = 0; s < 4; s++) {
            int iy = s >> 1;                  // 0,1
            int ix = px * 2 + (s & 1);
            int vy = s_v[iy], vx = s_v[2 + ix];
            if (vy & vx) {
                float fy = s_f[iy], fx = s_f[2 + ix];
                int ylo = s_lo[iy], yhi = s_hi[iy];
                int xlo = s_lo[2 + ix], xhi = s_hi[2 + ix];
                float v00 = bf2f(Fb[((size_t)ylo * HW + xlo) * CCH]);
                float v01 = bf2f(Fb[((size_t)ylo * HW + xhi) * CCH]);
                float v10 = bf2f(Fb[((size_t)yhi * HW + xlo) * CCH]);
                float v11 = bf2f(Fb[((size_t)yhi * HW + xhi) * CCH]);
                acc += (1.f - fy) * ((1.f - fx) * v00 + fx * v01)
                     + fy * ((1.f - fx) * v10 + fx * v11);
            }
        }
        xpool[obase + px * 256] = f2bf(acc * 0.25f);
    }
}

// NCHW fp32 fallback (only if ws too small for NHWC staging)
__global__ __launch_bounds__(256) void roi_align_nchw_k(const float* __restrict__ f0,
                                                        const float* __restrict__ f1,
                                                        const float* __restrict__ f2,
                                                        const float* __restrict__ f3,
                                                        const float* __restrict__ rois,
                                                        unsigned short* __restrict__ xpool) {
    __shared__ float s_f[16];
    __shared__ int   s_lo[16], s_hi[16], s_v[16];
    int py = blockIdx.x, r = blockIdx.y, t = threadIdx.x;
    float r0  = rois[r * 5 + 0];
    float rx1 = rois[r * 5 + 1], ry1 = rois[r * 5 + 2];
    float rx2 = rois[r * 5 + 3], ry2 = rois[r * 5 + 4];
    int b = (int)r0;
    float aw = rx2 - rx1 + 1.f, ah = ry2 - ry1 + 1.f;
    float lvf = floorf(log2f(sqrtf(ah * aw) / 56.f + 1e-6f));
    int lv = (int)fminf(fmaxf(lvf, 0.f), 3.f);
    const float* F = (lv == 0) ? f0 : (lv == 1) ? f1 : (lv == 2) ? f2 : f3;
    int HW      = (lv == 0) ? 200 : (lv == 1) ? 100 : (lv == 2) ? 50 : 25;
    float scale = (lv == 0) ? 0.25f : (lv == 1) ? 0.125f : (lv == 2) ? 0.0625f : 0.03125f;
    float x1 = rx1 * scale, yy1 = ry1 * scale;
    float x2 = rx2 * scale, yy2 = ry2 * scale;
    float rw = fmaxf(x2 - x1, 1.f), rh = fmaxf(yy2 - yy1, 1.f);
    if (t < 16) {
        bool isY = t < 2;
        float coord;
        if (isY) {
            float g = (float)py + ((float)t + 0.5f) * 0.5f;
            coord = yy1 + g * (rh * (1.f / 7.f));
        } else {
            int j = t - 2;
            float g = (float)(j >> 1) + ((float)(j & 1) + 0.5f) * 0.5f;
            coord = x1 + g * (rw * (1.f / 7.f));
        }
        int vld = (coord >= -1.f && coord <= (float)HW) ? 1 : 0;
        float c = fminf(fmaxf(coord, 0.f), (float)(HW - 1));
        int lo  = (int)floorf(c);
        int hi  = min(lo + 1, HW - 1);
        s_v[t] = vld; s_lo[t] = lo; s_hi[t] = hi; s_f[t] = c - (float)lo;
    }
    __syncthreads();
    const float* Fb = F + ((size_t)b * CCH + t) * HW * HW;
    size_t obase = (size_t)r * DDIM + py * 7 * 256 + t;
    for (int px = 0; px < POOLP; px++) {
        float acc = 0.f;
#pragma unroll
        for (int s = 0; s < 4; s++) {
            int iy = s >> 1, ix = px * 2 + (s & 1);
            int vy = s_v[iy], vx = s_v[2 + ix];
            if (vy & vx) {
                float fy = s_f[iy], fx = s_f[2 + ix];
                int ylo = s_lo[iy], yhi = s_hi[iy];
                int xlo = s_lo[2 + ix], xhi = s_hi[2 + ix];
                float v00 = Fb[(size_t)ylo * HW + xlo];
                float v01 = Fb[(size_t)ylo * HW + xhi];
                float v10 = Fb[(size_t)yhi * HW + xlo];
                float v11 = Fb[(size_t)yhi * HW + xhi];
                acc += (1.f - fy) * ((1.f - fx) * v00 + fx * v01)
                     + fy * ((1.f - fx) * v10 + fx * v11);
            }
        }
        xpool[obase + px * 256] = f2bf(acc * 0.25f);
    }
}

// ---------------------------------------------------------------------------
// 64x64 bf16 MFMA GEMM with split-K partials (FC2 / head).
__global__ __launch_bounds__(256) void gemm_bf16_k(const unsigned short* __restrict__ A,
                                                   const unsigned short* __restrict__ W,
                                                   float* __restrict__ Cp,
                                                   int M, int N, int K, int kchunk) {
    __shared__ __align__(16) unsigned short As[8][64][8];
    __shared__ __align__(16) unsigned short Ws[8][64][8];

    int t = threadIdx.x;
    int lane = t & 63, wid = t >> 6;
    int m0 = blockIdx.y * 64, n0 = blockIdx.x * 64;
    int k0 = blockIdx.z * kchunk;
    int wm = (wid >> 1) * 32, wn = (wid & 1) * 32;
    int fr = lane & 15, kg = lane >> 4;

    f32x4 acc[2][2] = {};

    const unsigned short* Arow = A + (size_t)(m0 + lane) * K;
    const unsigned short* Wrow = W + (size_t)(n0 + lane) * K;

    for (int kb = k0; kb < k0 + kchunk; kb += 64) {
#pragma unroll
        for (int i = 0; i < 2; i++) {
            int c = wid * 2 + i;
            __builtin_amdgcn_global_load_lds(
                (const __attribute__((address_space(1))) void*)(Arow + kb + c * 8),
                (__attribute__((address_space(3))) void*)(&As[c][0][0]), 16, 0, 0);
            __builtin_amdgcn_global_load_lds(
                (const __attribute__((address_space(1))) void*)(Wrow + kb + c * 8),
                (__attribute__((address_space(3))) void*)(&Ws[c][0][0]), 16, 0, 0);
        }
        __syncthreads();
#pragma unroll
        for (int h = 0; h < 2; h++) {
            bf16x8 a0 = *(const bf16x8*)(&As[h * 4 + kg][wm + fr][0]);
            bf16x8 a1 = *(const bf16x8*)(&As[h * 4 + kg][wm + 16 + fr][0]);
            bf16x8 b0 = *(const bf16x8*)(&Ws[h * 4 + kg][wn + fr][0]);
            bf16x8 b1 = *(const bf16x8*)(&Ws[h * 4 + kg][wn + 16 + fr][0]);
            acc[0][0] = __builtin_amdgcn_mfma_f32_16x16x32_bf16(a0, b0, acc[0][0], 0, 0, 0);
            acc[0][1] = __builtin_amdgcn_mfma_f32_16x16x32_bf16(a0, b1, acc[0][1], 0, 0, 0);
            acc[1][0] = __builtin_amdgcn_mfma_f32_16x16x32_bf16(a1, b0, acc[1][0], 0, 0, 0);
            acc[1][1] = __builtin_amdgcn_mfma_f32_16x16x32_bf16(a1, b1, acc[1][1], 0, 0, 0);
        }
        __syncthreads();
    }

    float* Cout = Cp + (size_t)blockIdx.z * M * N;
    int row = m0 + wm + (lane >> 4) * 4;
    int col = n0 + wn + (lane & 15);
#pragma unroll
    for (int fm = 0; fm < 2; fm++)
#pragma unroll
        for (int fn = 0; fn < 2; fn++)
#pragma unroll
            for (int r = 0; r < 4; r++)
                Cout[(size_t)(row + fm * 16 + r) * N + col + fn * 16] = acc[fm][fn][r];
}

// ---------------------------------------------------------------------------
// 128x128 bf16 MFMA GEMM with split-K partials (FC1). 4 waves, 64x64 per wave.
__global__ __launch_bounds__(256) void gemm128_bf16_k(const unsigned short* __restrict__ A,
                                                      const unsigned short* __restrict__ W,
                                                      float* __restrict__ Cp,
                                                      int M, int N, int K, int kchunk) {
    __shared__ __align__(16) unsigned short As[8][128][8];   // 16 KB
    __shared__ __align__(16) unsigned short Ws[8][128][8];   // 16 KB

    int t = threadIdx.x;
    int lane = t & 63, wid = t >> 6;
    int m0 = blockIdx.y * 128, n0 = blockIdx.x * 128;
    int k0 = blockIdx.z * kchunk;
    int wm = (wid >> 1) * 64, wn = (wid & 1) * 64;
    int fr = lane & 15, kg = lane >> 4;

    f32x4 acc[4][4] = {};

    for (int kb = k0; kb < k0 + kchunk; kb += 64) {
#pragma unroll
        for (int i = 0; i < 4; i++) {
            int c   = wid * 4 + i;             // 0..15, wave-uniform
            int kgc = c >> 1;
            int r0w = (c & 1) * 64;
            __builtin_amdgcn_global_load_lds(
                (const __attribute__((address_space(1))) void*)
                    (A + (size_t)(m0 + r0w + lane) * K + kb + kgc * 8),
                (__attribute__((address_space(3))) void*)(&As[kgc][r0w][0]), 16, 0, 0);
            __builtin_amdgcn_global_load_lds(
                (const __attribute__((address_space(1))) void*)
                    (W + (size_t)(n0 + r0w + lane) * K + kb + kgc * 8),
                (__attribute__((address_space(3))) void*)(&Ws[kgc][r0w][0]), 16, 0, 0);
        }
        __syncthreads();
#pragma unroll
        for (int h = 0; h < 2; h++) {
            bf16x8 av[4], bv[4];
#pragma unroll
            for (int f = 0; f < 4; f++) {
                av[f] = *(const bf16x8*)(&As[h * 4 + kg][wm + f * 16 + fr][0]);
                bv[f] = *(const bf16x8*)(&Ws[h * 4 + kg][wn + f * 16 + fr][0]);
            }
#pragma unroll
            for (int fm = 0; fm < 4; fm++)
#pragma unroll
                for (int fn = 0; fn < 4; fn++)
                    acc[fm][fn] = __builtin_amdgcn_mfma_f32_16x16x32_bf16(
                        av[fm], bv[fn], acc[fm][fn], 0, 0, 0);
        }
        __syncthreads();
    }

    float* Cout = Cp + (size_t)blockIdx.z * M * N;
    int row = m0 + wm + (lane >> 4) * 4;
    int col = n0 + wn + (lane & 15);
#pragma unroll
    for (int fm = 0; fm < 4; fm++)
#pragma unroll
        for (int fn = 0; fn < 4; fn++)
#pragma unroll
            for (int r = 0; r < 4; r++)
                Cout[(size_t)(row + fm * 16 + r) * N + col + fn * 16] = acc[fm][fn][r];
}

// ---------------------------------------------------------------------------
__global__ __launch_bounds__(256) void reduce_relu_k(const float* __restrict__ Cp,
                                                     const float* __restrict__ bias,
                                                     unsigned short* __restrict__ out,
                                                     int MN, int ks) {
    int i = blockIdx.x * 256 + threadIdx.x;
    if (i >= MN) return;
    float s = 0.f;
    for (int p = 0; p < ks; p++) s += Cp[(size_t)p * MN + i];
    s = fmaxf(s + bias[i & (HIDN - 1)], 0.f);
    out[i] = f2bf(s);
}

__global__ __launch_bounds__(256) void head_reduce_k(const float* __restrict__ Cp,
                                                     const float* __restrict__ bc,
                                                     const float* __restrict__ br,
                                                     float* __restrict__ cls_logits,
                                                     float* __restrict__ reg_out, int ks) {
    int i = blockIdx.x * 256 + threadIdx.x;   // 512*512
    int r = i >> 9, c = i & 511;
    float s = 0.f;
    for (int p = 0; p < ks; p++) s += Cp[(size_t)p * (512 * 512) + i];
    if (c < NCLS) cls_logits[r * NCLS + c] = s + bc[c];
    else if (c < NCLS + NREG) reg_out[r * NREG + (c - NCLS)] = s + br[c - NCLS];
}

// ---------------------------------------------------------------------------
__global__ void softmax81_k(const float* __restrict__ logits, float* __restrict__ out) {
    int r = blockIdx.x;
    int l = threadIdx.x;  // 0..63
    float v0 = logits[r * NCLS + l];
    float v1 = (l + 64 < NCLS) ? logits[r * NCLS + l + 64] : -INFINITY;
    float m = fmaxf(v0, v1);
#pragma unroll
    for (int o = 32; o; o >>= 1) m = fmaxf(m, __shfl_xor(m, o));
    float e0 = __expf(v0 - m);
    float e1 = (l + 64 < NCLS) ? __expf(v1 - m) : 0.f;
    float s = e0 + e1;
#pragma unroll
    for (int o = 32; o; o >>= 1) s += __shfl_xor(s, o);
    float inv = 1.f / s;
    out[r * NCLS + l] = e0 * inv;
    if (l + 64 < NCLS) out[r * NCLS + l + 64] = e1 * inv;
}

// ---------------------------------------------------------------------------
extern "C" void kernel_launch(void* const* d_in, const int* in_sizes, int n_in,
                              void* d_out, int out_size, void* d_ws, size_t ws_size,
                              hipStream_t stream) {
    const float* p2   = (const float*)d_in[0];
    const float* p3   = (const float*)d_in[1];
    const float* p4   = (const float*)d_in[2];
    const float* p5   = (const float*)d_in[3];
    const float* rois = (const float*)d_in[4];
    const float* w1   = (const float*)d_in[5];
    const float* b1   = (const float*)d_in[6];
    const float* w2   = (const float*)d_in[7];
    const float* b2   = (const float*)d_in[8];
    const float* wc   = (const float*)d_in[9];
    const float* bc   = (const float*)d_in[10];
    const float* wr   = (const float*)d_in[11];
    const float* br   = (const float*)d_in[12];

    float* out = (float*)d_out;

    const int KS1 = 14;   // FC1 split-K (12544 = 14 * 896)

    // workspace carve-up (256B-aligned chunks)
    char* p = (char*)d_ws;
    auto alloc = [&](size_t bytes) { char* r = p; p += (bytes + 255) & ~(size_t)255; return r; };
    unsigned short* xpool = (unsigned short*)alloc((size_t)NROI * DDIM * 2);    // 12.8 MB
    unsigned short* y1b   = (unsigned short*)alloc((size_t)NROI * HIDN * 2);
    unsigned short* y2b   = (unsigned short*)alloc((size_t)NROI * HIDN * 2);
    unsigned short* w1b   = (unsigned short*)alloc((size_t)HIDN * DDIM * 2);    // 25.7 MB
    unsigned short* w2b   = (unsigned short*)alloc((size_t)HIDN * HIDN * 2);
    unsigned short* whd   = (unsigned short*)alloc((size_t)NHEAD * HIDN * 2);
    float*          clsl  = (float*)alloc((size_t)NROI * NCLS * 4);
    float*          part  = (float*)alloc((size_t)KS1 * NROI * HIDN * 4);       // 29.4 MB
    unsigned short* ft0 = (unsigned short*)alloc((size_t)2 * 40000 * CCH * 2);  // 41 MB
    unsigned short* ft1 = (unsigned short*)alloc((size_t)2 * 10000 * CCH * 2);
    unsigned short* ft2 = (unsigned short*)alloc((size_t)2 * 2500 * CCH * 2);
    unsigned short* ft3 = (unsigned short*)alloc((size_t)2 * 625 * CCH * 2);
    bool nhwc = (size_t)(p - (char*)d_ws) <= ws_size;

    copy_rois_k<<<(OUT_ROIS + 255) / 256, 256, 0, stream>>>(rois, out);

    // weight conversions
    permute_w1_k<<<HIDN, 256, 0, stream>>>(w1, w1b);
    cvt_bf16_k<<<(HIDN * HIDN / 4 + 255) / 256, 256, 0, stream>>>(
        (const float4*)w2, (ushort4*)w2b, HIDN * HIDN / 4);
    pack_head_k<<<(NHEAD * HIDN + 255) / 256, 256, 0, stream>>>(wc, wr, whd);

    if (nhwc) {
        dim3 blk(32, 8);
        transpose_cvt_k<<<dim3(1250, 8, 2), blk, 0, stream>>>(p2, ft0, 40000);
        transpose_cvt_k<<<dim3(313, 8, 2),  blk, 0, stream>>>(p3, ft1, 10000);
        transpose_cvt_k<<<dim3(79, 8, 2),   blk, 0, stream>>>(p4, ft2, 2500);
        transpose_cvt_k<<<dim3(20, 8, 2),   blk, 0, stream>>>(p5, ft3, 625);
        roi_align_k<<<dim3(POOLP, NROI), 256, 0, stream>>>(ft0, ft1, ft2, ft3, rois, xpool);
    } else {
        roi_align_nchw_k<<<dim3(POOLP, NROI), 256, 0, stream>>>(p2, p3, p4, p5, rois, xpool);
    }

    // FC1: (512,12544)x(1024,12544)^T, 128^2 tile, split-K 14
    gemm128_bf16_k<<<dim3(HIDN / 128, NROI / 128, KS1), 256, 0, stream>>>(
        xpool, w1b, part, NROI, HIDN, DDIM, DDIM / KS1);
    reduce_relu_k<<<(NROI * HIDN + 255) / 256, 256, 0, stream>>>(
        part, b1, y1b, NROI * HIDN, KS1);

    // FC2: (512,1024)x(1024,1024)^T, split-K 2
    gemm_bf16_k<<<dim3(HIDN / 64, NROI / 64, 2), 256, 0, stream>>>(
        y1b, w2b, part, NROI, HIDN, HIDN, HIDN / 2);
    reduce_relu_k<<<(NROI * HIDN + 255) / 256, 256, 0, stream>>>(
        part, b2, y2b, NROI * HIDN, 2);

    // head: (512,1024)x(512,1024)^T, split-K 4
    gemm_bf16_k<<<dim3(NHEAD / 64, NROI / 64, 4), 256, 0, stream>>>(
        y2b, whd, part, NROI, NHEAD, HIDN, HIDN / 4);
    head_reduce_k<<<(NROI * NHEAD + 255) / 256, 256, 0, stream>>>(
        part, bc, br, clsl, out + OUT_ROIS + OUT_CLS, 4);

    softmax81_k<<<NROI, 64, 0, stream>>>(clsl, out + OUT_ROIS);
}

// Round 4
// 163.160 us; speedup vs baseline: 10.3231x; 1.0567x over previous
//
#include <hip/hip_runtime.h>
#include <hip/hip_bf16.h>
#include <math.h>

// Problem constants
#define NROI   512
#define CCH    256
#define POOLP  7
#define DDIM   12544   // 256*7*7
#define HIDN   1024
#define NCLS   81
#define NREG   324
#define NHEAD  512           // padded head N: 81 cls + 324 reg + 107 pad
#define OUT_ROIS   2560      // 2*256*5
#define OUT_CLS    (512*81)

typedef __attribute__((ext_vector_type(4))) float f32x4;
typedef __attribute__((ext_vector_type(8))) short bf16x8;

static __device__ __forceinline__ unsigned short f2bf(float x) {
    __hip_bfloat16 h = __float2bfloat16(x);
    return *reinterpret_cast<unsigned short*>(&h);
}
static __device__ __forceinline__ float bf2f(unsigned short u) {
    unsigned int b = ((unsigned int)u) << 16;
    return *reinterpret_cast<float*>(&b);
}

// ---------------------------------------------------------------------------
// prep: [0,10) rois copy | [10,1290) zero acc (5MB) | [1290,2314) w2 cvt
//       | [2314,3338) head pack
#define PREP_B0 10
#define PREP_B1 (PREP_B0 + 1280)
#define PREP_B2 (PREP_B1 + 1024)
#define PREP_B3 (PREP_B2 + 1024)
__global__ __launch_bounds__(256) void prep_k(const float* __restrict__ rois,
                                              const float* __restrict__ w2,
                                              const float* __restrict__ wc,
                                              const float* __restrict__ wr,
                                              float* __restrict__ out,
                                              float* __restrict__ accz,      // 1.25M floats
                                              unsigned short* __restrict__ w2b,
                                              unsigned short* __restrict__ whd) {
    int bid = blockIdx.x, t = threadIdx.x;
    if (bid < PREP_B0) {
        int i = bid * 256 + t;
        if (i < OUT_ROIS) out[i] = rois[i];
    } else if (bid < PREP_B1) {
        int i = (bid - PREP_B0) * 256 + t;            // float4 index, 327680 total
        ((float4*)accz)[i] = make_float4(0.f, 0.f, 0.f, 0.f);
    } else if (bid < PREP_B2) {
        int i = (bid - PREP_B1) * 256 + t;            // float4 index, 262144 total
        float4 v = ((const float4*)w2)[i];
        ushort4 o;
        o.x = f2bf(v.x); o.y = f2bf(v.y); o.z = f2bf(v.z); o.w = f2bf(v.w);
        ((ushort4*)w2b)[i] = o;
    } else {
        int i2 = (bid - PREP_B2) * 256 + t;           // ushort2 index, 262144 total
        int r = i2 >> 9, c = (i2 & 511) << 1;
        float v0, v1;
        if (r < NCLS)             { v0 = wc[r * HIDN + c]; v1 = wc[r * HIDN + c + 1]; }
        else if (r < NCLS + NREG) { v0 = wr[(r - NCLS) * HIDN + c]; v1 = wr[(r - NCLS) * HIDN + c + 1]; }
        else                      { v0 = 0.f; v1 = 0.f; }
        ((unsigned int*)whd)[i2] = (unsigned int)f2bf(v0) | ((unsigned int)f2bf(v1) << 16);
    }
}

// ---------------------------------------------------------------------------
// w1 column-permute + bf16: w1b[n][s*256+c] = w1[n][c*49+s]  (s=py*7+px)
__global__ __launch_bounds__(256) void permute_w1_k(const float* __restrict__ w1,
                                                    unsigned short* __restrict__ w1b) {
    __shared__ unsigned short lw[49 * 258];
    int n = blockIdx.x, t = threadIdx.x;
    const float* src = w1 + (size_t)n * DDIM;
#pragma unroll
    for (int k = t; k < DDIM; k += 256) {
        int c = k / 49;
        int s = k - c * 49;
        lw[s * 258 + c] = f2bf(src[k]);
    }
    __syncthreads();
    unsigned int* dst = (unsigned int*)(w1b + (size_t)n * DDIM);
    for (int j2 = t; j2 < DDIM / 2; j2 += 256) {
        int s  = j2 >> 7;
        int c2 = (j2 & 127) << 1;
        dst[j2] = lw[s * 258 + c2] | ((unsigned int)lw[s * 258 + c2 + 1] << 16);
    }
}

// ---------------------------------------------------------------------------
// merged NCHW fp32 -> NHWC bf16 transpose, all 4 levels in one launch.
// x-block ranges: [0,1250) S=40000 | [1250,1563) S=10000 | [1563,1642) S=2500
//                 | [1642,1662) S=625.  tile: 32 s x 64 c.
__global__ __launch_bounds__(256) void transpose_all_k(const float* __restrict__ p2,
                                                       const float* __restrict__ p3,
                                                       const float* __restrict__ p4,
                                                       const float* __restrict__ p5,
                                                       unsigned short* __restrict__ f0,
                                                       unsigned short* __restrict__ f1,
                                                       unsigned short* __restrict__ f2,
                                                       unsigned short* __restrict__ f3) {
    __shared__ unsigned short tile[32][66];
    int xb = blockIdx.x;
    const float* in; unsigned short* outp; int S, base;
    if (xb < 1250)      { in = p2; outp = f0; S = 40000; base = 0; }
    else if (xb < 1563) { in = p3; outp = f1; S = 10000; base = 1250; }
    else if (xb < 1642) { in = p4; outp = f2; S = 2500;  base = 1563; }
    else                { in = p5; outp = f3; S = 625;   base = 1642; }
    int s0 = (xb - base) * 32;
    int c0 = blockIdx.y * 64;
    int b  = blockIdx.z;
    int t  = threadIdx.x;

    // load: lanes 0..31 = consecutive s (coalesced fp32), 8 c each
    {
        int sL = t & 31, cq = t >> 5;
        const float* src = in + ((size_t)b * CCH + c0 + cq * 8) * S + s0 + sL;
        bool ok = (s0 + sL) < S;
#pragma unroll
        for (int j = 0; j < 8; j++)
            tile[sL][cq * 8 + j] = ok ? f2bf(src[(size_t)j * S]) : (unsigned short)0;
    }
    __syncthreads();
    // store: lanes 0..31 = consecutive c-pairs (coalesced uint), 4 s each
    {
        int c2 = t & 31, sq = t >> 5;
#pragma unroll
        for (int i = 0; i < 4; i++) {
            int s = sq * 4 + i;
            if (s0 + s < S) {
                unsigned int v = tile[s][c2 * 2] | ((unsigned int)tile[s][c2 * 2 + 1] << 16);
                ((unsigned int*)(outp + ((size_t)b * S + s0 + s) * CCH + c0))[c2] = v;
            }
        }
    }
}

// ---------------------------------------------------------------------------
// ROI Align, block per (py, roi), 256 threads = channels, bf16 NHWC features.
// xpool[r][ (py*7+px)*256 + c ]  (k-permuted layout, matches permute_w1_k)
__global__ __launch_bounds__(256) void roi_align_k(const unsigned short* __restrict__ f0,
                                                   const unsigned short* __restrict__ f1,
                                                   const unsigned short* __restrict__ f2,
                                                   const unsigned short* __restrict__ f3,
                                                   const float* __restrict__ rois,
                                                   unsigned short* __restrict__ xpool) {
    __shared__ float s_f[16];
    __shared__ int   s_lo[16], s_hi[16], s_v[16];

    int py = blockIdx.x, r = blockIdx.y, t = threadIdx.x;

    float r0  = rois[r * 5 + 0];
    float rx1 = rois[r * 5 + 1], ry1 = rois[r * 5 + 2];
    float rx2 = rois[r * 5 + 3], ry2 = rois[r * 5 + 4];
    int b = (int)r0;

    float aw = rx2 - rx1 + 1.f, ah = ry2 - ry1 + 1.f;
    float lvf = floorf(log2f(sqrtf(ah * aw) / 56.f + 1e-6f));
    int lv = (int)fminf(fmaxf(lvf, 0.f), 3.f);

    const unsigned short* F = (lv == 0) ? f0 : (lv == 1) ? f1 : (lv == 2) ? f2 : f3;
    int HW      = (lv == 0) ? 200 : (lv == 1) ? 100 : (lv == 2) ? 50 : 25;
    float scale = (lv == 0) ? 0.25f : (lv == 1) ? 0.125f : (lv == 2) ? 0.0625f : 0.03125f;

    float x1 = rx1 * scale, yy1 = ry1 * scale;
    float x2 = rx2 * scale, yy2 = ry2 * scale;
    float rw = fmaxf(x2 - x1, 1.f), rh = fmaxf(yy2 - yy1, 1.f);

    if (t < 16) {
        bool isY = t < 2;
        float coord;
        if (isY) {
            float g = (float)py + ((float)t + 0.5f) * 0.5f;
            coord = yy1 + g * (rh * (1.f / 7.f));
        } else {
            int j = t - 2;
            float g = (float)(j >> 1) + ((float)(j & 1) + 0.5f) * 0.5f;
            coord = x1 + g * (rw * (1.f / 7.f));
        }
        int vld = (coord >= -1.f && coord <= (float)HW) ? 1 : 0;
        float c = fminf(fmaxf(coord, 0.f), (float)(HW - 1));
        int lo  = (int)floorf(c);
        int hi  = min(lo + 1, HW - 1);
        s_v[t] = vld; s_lo[t] = lo; s_hi[t] = hi; s_f[t] = c - (float)lo;
    }
    __syncthreads();

    const unsigned short* Fb = F + ((size_t)b * HW * HW) * CCH + t;
    size_t obase = (size_t)r * DDIM + py * 7 * 256 + t;

    for (int px = 0; px < POOLP; px++) {
        float acc = 0.f;
#pragma unroll
        for (int s = 0; s < 4; s++) {
            int iy = s >> 1;
            int ix = px * 2 + (s & 1);
            int vy = s_v[iy], vx = s_v[2 + ix];
            if (vy & vx) {
                float fy = s_f[iy], fx = s_f[2 + ix];
                int ylo = s_lo[iy], yhi = s_hi[iy];
                int xlo = s_lo[2 + ix], xhi = s_hi[2 + ix];
                float v00 = bf2f(Fb[((size_t)ylo * HW + xlo) * CCH]);
                float v01 = bf2f(Fb[((size_t)ylo * HW + xhi) * CCH]);
                float v10 = bf2f(Fb[((size_t)yhi * HW + xlo) * CCH]);
                float v11 = bf2f(Fb[((size_t)yhi * HW + xhi) * CCH]);
                acc += (1.f - fy) * ((1.f - fx) * v00 + fx * v01)
                     + fy * ((1.f - fx) * v10 + fx * v11);
            }
        }
        xpool[obase + px * 256] = f2bf(acc * 0.25f);
    }
}

// NCHW fp32 fallback (only if ws too small for NHWC staging)
__global__ __launch_bounds__(256) void roi_align_nchw_k(const float* __restrict__ f0,
                                                        const float* __restrict__ f1,
                                                        const float* __restrict__ f2,
                                                        const float* __restrict__ f3,
                                                        const float* __restrict__ rois,
                                                        unsigned short* __restrict__ xpool) {
    __shared__ float s_f[16];
    __shared__ int   s_lo[16], s_hi[16], s_v[16];
    int py = blockIdx.x, r = blockIdx.y, t = threadIdx.x;
    float r0  = rois[r * 5 + 0];
    float rx1 = rois[r * 5 + 1], ry1 = rois[r * 5 + 2];
    float rx2 = rois[r * 5 + 3], ry2 = rois[r * 5 + 4];
    int b = (int)r0;
    float aw = rx2 - rx1 + 1.f, ah = ry2 - ry1 + 1.f;
    float lvf = floorf(log2f(sqrtf(ah * aw) / 56.f + 1e-6f));
    int lv = (int)fminf(fmaxf(lvf, 0.f), 3.f);
    const float* F = (lv == 0) ? f0 : (lv == 1) ? f1 : (lv == 2) ? f2 : f3;
    int HW      = (lv == 0) ? 200 : (lv == 1) ? 100 : (lv == 2) ? 50 : 25;
    float scale = (lv == 0) ? 0.25f : (lv == 1) ? 0.125f : (lv == 2) ? 0.0625f : 0.03125f;
    float x1 = rx1 * scale, yy1 = ry1 * scale;
    float x2 = rx2 * scale, yy2 = ry2 * scale;
    float rw = fmaxf(x2 - x1, 1.f), rh = fmaxf(yy2 - yy1, 1.f);
    if (t < 16) {
        bool isY = t < 2;
        float coord;
        if (isY) {
            float g = (float)py + ((float)t + 0.5f) * 0.5f;
            coord = yy1 + g * (rh * (1.f / 7.f));
        } else {
            int j = t - 2;
            float g = (float)(j >> 1) + ((float)(j & 1) + 0.5f) * 0.5f;
            coord = x1 + g * (rw * (1.f / 7.f));
        }
        int vld = (coord >= -1.f && coord <= (float)HW) ? 1 : 0;
        float c = fminf(fmaxf(coord, 0.f), (float)(HW - 1));
        int lo  = (int)floorf(c);
        int hi  = min(lo + 1, HW - 1);
        s_v[t] = vld; s_lo[t] = lo; s_hi[t] = hi; s_f[t] = c - (float)lo;
    }
    __syncthreads();
    const float* Fb = F + ((size_t)b * CCH + t) * HW * HW;
    size_t obase = (size_t)r * DDIM + py * 7 * 256 + t;
    for (int px = 0; px < POOLP; px++) {
        float acc = 0.f;
#pragma unroll
        for (int s = 0; s < 4; s++) {
            int iy = s >> 1, ix = px * 2 + (s & 1);
            int vy = s_v[iy], vx = s_v[2 + ix];
            if (vy & vx) {
                float fy = s_f[iy], fx = s_f[2 + ix];
                int ylo = s_lo[iy], yhi = s_hi[iy];
                int xlo = s_lo[2 + ix], xhi = s_hi[2 + ix];
                float v00 = Fb[(size_t)ylo * HW + xlo];
                float v01 = Fb[(size_t)ylo * HW + xhi];
                float v10 = Fb[(size_t)yhi * HW + xlo];
                float v11 = Fb[(size_t)yhi * HW + xhi];
                acc += (1.f - fy) * ((1.f - fx) * v00 + fx * v01)
                     + fy * ((1.f - fx) * v10 + fx * v11);
            }
        }
        xpool[obase + px * 256] = f2bf(acc * 0.25f);
    }
}

// ---------------------------------------------------------------------------
// 64x64 bf16 MFMA GEMM, split-K via atomicAdd into fp32 accumulator (FC2/head).
__global__ __launch_bounds__(256) void gemm_bf16_k(const unsigned short* __restrict__ A,
                                                   const unsigned short* __restrict__ W,
                                                   float* __restrict__ Cacc,
                                                   int M, int N, int K, int kchunk) {
    __shared__ __align__(16) unsigned short As[8][64][8];
    __shared__ __align__(16) unsigned short Ws[8][64][8];

    int t = threadIdx.x;
    int lane = t & 63, wid = t >> 6;
    int m0 = blockIdx.y * 64, n0 = blockIdx.x * 64;
    int k0 = blockIdx.z * kchunk;
    int wm = (wid >> 1) * 32, wn = (wid & 1) * 32;
    int fr = lane & 15, kg = lane >> 4;

    f32x4 acc[2][2] = {};

    const unsigned short* Arow = A + (size_t)(m0 + lane) * K;
    const unsigned short* Wrow = W + (size_t)(n0 + lane) * K;

    for (int kb = k0; kb < k0 + kchunk; kb += 64) {
#pragma unroll
        for (int i = 0; i < 2; i++) {
            int c = wid * 2 + i;
            __builtin_amdgcn_global_load_lds(
                (const __attribute__((address_space(1))) void*)(Arow + kb + c * 8),
                (__attribute__((address_space(3))) void*)(&As[c][0][0]), 16, 0, 0);
            __builtin_amdgcn_global_load_lds(
                (const __attribute__((address_space(1))) void*)(Wrow + kb + c * 8),
                (__attribute__((address_space(3))) void*)(&Ws[c][0][0]), 16, 0, 0);
        }
        __syncthreads();
#pragma unroll
        for (int h = 0; h < 2; h++) {
            bf16x8 a0 = *(const bf16x8*)(&As[h * 4 + kg][wm + fr][0]);
            bf16x8 a1 = *(const bf16x8*)(&As[h * 4 + kg][wm + 16 + fr][0]);
            bf16x8 b0 = *(const bf16x8*)(&Ws[h * 4 + kg][wn + fr][0]);
            bf16x8 b1 = *(const bf16x8*)(&Ws[h * 4 + kg][wn + 16 + fr][0]);
            acc[0][0] = __builtin_amdgcn_mfma_f32_16x16x32_bf16(a0, b0, acc[0][0], 0, 0, 0);
            acc[0][1] = __builtin_amdgcn_mfma_f32_16x16x32_bf16(a0, b1, acc[0][1], 0, 0, 0);
            acc[1][0] = __builtin_amdgcn_mfma_f32_16x16x32_bf16(a1, b0, acc[1][0], 0, 0, 0);
            acc[1][1] = __builtin_amdgcn_mfma_f32_16x16x32_bf16(a1, b1, acc[1][1], 0, 0, 0);
        }
        __syncthreads();
    }

    int row = m0 + wm + (lane >> 4) * 4;
    int col = n0 + wn + (lane & 15);
#pragma unroll
    for (int fm = 0; fm < 2; fm++)
#pragma unroll
        for (int fn = 0; fn < 2; fn++)
#pragma unroll
            for (int r = 0; r < 4; r++)
                atomicAdd(&Cacc[(size_t)(row + fm * 16 + r) * N + col + fn * 16],
                          acc[fm][fn][r]);
}

// ---------------------------------------------------------------------------
// 128x128 bf16 MFMA GEMM (FC1), split-K atomics, XCD-chunked block swizzle.
// grid = 448 linear blocks: (x=N/128=8) x (y=M/128=4) x (z=KS=14)
__global__ __launch_bounds__(256) void gemm128_bf16_k(const unsigned short* __restrict__ A,
                                                      const unsigned short* __restrict__ W,
                                                      float* __restrict__ Cacc,
                                                      int M, int N, int K, int kchunk) {
    __shared__ __align__(16) unsigned short As[8][128][8];
    __shared__ __align__(16) unsigned short Ws[8][128][8];

    // XCD-chunked swizzle (448 % 8 == 0 -> bijective)
    int lin = blockIdx.x;
    int nb  = (lin & 7) * 56 + (lin >> 3);
    int bx = nb & 7, by = (nb >> 3) & 3, bz = nb >> 5;

    int t = threadIdx.x;
    int lane = t & 63, wid = t >> 6;
    int m0 = by * 128, n0 = bx * 128;
    int k0 = bz * kchunk;
    int wm = (wid >> 1) * 64, wn = (wid & 1) * 64;
    int fr = lane & 15, kg = lane >> 4;

    f32x4 acc[4][4] = {};

    for (int kb = k0; kb < k0 + kchunk; kb += 64) {
#pragma unroll
        for (int i = 0; i < 4; i++) {
            int c   = wid * 4 + i;
            int kgc = c >> 1;
            int r0w = (c & 1) * 64;
            __builtin_amdgcn_global_load_lds(
                (const __attribute__((address_space(1))) void*)
                    (A + (size_t)(m0 + r0w + lane) * K + kb + kgc * 8),
                (__attribute__((address_space(3))) void*)(&As[kgc][r0w][0]), 16, 0, 0);
            __builtin_amdgcn_global_load_lds(
                (const __attribute__((address_space(1))) void*)
                    (W + (size_t)(n0 + r0w + lane) * K + kb + kgc * 8),
                (__attribute__((address_space(3))) void*)(&Ws[kgc][r0w][0]), 16, 0, 0);
        }
        __syncthreads();
#pragma unroll
        for (int h = 0; h < 2; h++) {
            bf16x8 av[4], bv[4];
#pragma unroll
            for (int f = 0; f < 4; f++) {
                av[f] = *(const bf16x8*)(&As[h * 4 + kg][wm + f * 16 + fr][0]);
                bv[f] = *(const bf16x8*)(&Ws[h * 4 + kg][wn + f * 16 + fr][0]);
            }
#pragma unroll
            for (int fm = 0; fm < 4; fm++)
#pragma unroll
                for (int fn = 0; fn < 4; fn++)
                    acc[fm][fn] = __builtin_amdgcn_mfma_f32_16x16x32_bf16(
                        av[fm], bv[fn], acc[fm][fn], 0, 0, 0);
        }
        __syncthreads();
    }

    int row = m0 + wm + (lane >> 4) * 4;
    int col = n0 + wn + (lane & 15);
#pragma unroll
    for (int fm = 0; fm < 4; fm++)
#pragma unroll
        for (int fn = 0; fn < 4; fn++)
#pragma unroll
            for (int r = 0; r < 4; r++)
                atomicAdd(&Cacc[(size_t)(row + fm * 16 + r) * N + col + fn * 16],
                          acc[fm][fn][r]);
}

// ---------------------------------------------------------------------------
// fp32 accumulator + bias -> relu -> bf16  (N == HIDN)
__global__ __launch_bounds__(256) void fc_ep_k(const float* __restrict__ acc,
                                               const float* __restrict__ bias,
                                               unsigned short* __restrict__ dst, int MN) {
    int i = blockIdx.x * 256 + threadIdx.x;
    if (i >= MN) return;
    float s = fmaxf(acc[i] + bias[i & (HIDN - 1)], 0.f);
    dst[i] = f2bf(s);
}

// head accumulator (512x512) -> bias + reg out + softmax(cls) out. Block = roi.
__global__ void head_ep_k(const float* __restrict__ hf,
                          const float* __restrict__ bc,
                          const float* __restrict__ br,
                          float* __restrict__ out) {
    int r = blockIdx.x, l = threadIdx.x;   // 64 threads
    const float* row = hf + (size_t)r * NHEAD;

    float* reg = out + OUT_ROIS + OUT_CLS + (size_t)r * NREG;
    for (int j = l; j < NREG; j += 64) reg[j] = row[NCLS + j] + br[j];

    float v0 = row[l] + bc[l];
    float v1 = (l + 64 < NCLS) ? row[l + 64] + bc[l + 64] : -INFINITY;
    float m = fmaxf(v0, v1);
#pragma unroll
    for (int o = 32; o; o >>= 1) m = fmaxf(m, __shfl_xor(m, o));
    float e0 = __expf(v0 - m);
    float e1 = (l + 64 < NCLS) ? __expf(v1 - m) : 0.f;
    float s = e0 + e1;
#pragma unroll
    for (int o = 32; o; o >>= 1) s += __shfl_xor(s, o);
    float inv = 1.f / s;
    float* cls = out + OUT_ROIS + (size_t)r * NCLS;
    cls[l] = e0 * inv;
    if (l + 64 < NCLS) cls[l + 64] = e1 * inv;
}

// ---------------------------------------------------------------------------
extern "C" void kernel_launch(void* const* d_in, const int* in_sizes, int n_in,
                              void* d_out, int out_size, void* d_ws, size_t ws_size,
                              hipStream_t stream) {
    const float* p2   = (const float*)d_in[0];
    const float* p3   = (const float*)d_in[1];
    const float* p4   = (const float*)d_in[2];
    const float* p5   = (const float*)d_in[3];
    const float* rois = (const float*)d_in[4];
    const float* w1   = (const float*)d_in[5];
    const float* b1   = (const float*)d_in[6];
    const float* w2   = (const float*)d_in[7];
    const float* b2   = (const float*)d_in[8];
    const float* wc   = (const float*)d_in[9];
    const float* bc   = (const float*)d_in[10];
    const float* wr   = (const float*)d_in[11];
    const float* br   = (const float*)d_in[12];

    float* out = (float*)d_out;

    const int KS1 = 14;   // FC1 split-K (12544 = 14 * 896)

    // workspace carve-up (256B-aligned chunks)
    char* p = (char*)d_ws;
    auto alloc = [&](size_t bytes) { char* r = p; p += (bytes + 255) & ~(size_t)255; return r; };
    unsigned short* xpool = (unsigned short*)alloc((size_t)NROI * DDIM * 2);    // 12.8 MB
    unsigned short* y1b   = (unsigned short*)alloc((size_t)NROI * HIDN * 2);
    unsigned short* y2b   = (unsigned short*)alloc((size_t)NROI * HIDN * 2);
    unsigned short* w1b   = (unsigned short*)alloc((size_t)HIDN * DDIM * 2);    // 25.7 MB
    unsigned short* w2b   = (unsigned short*)alloc((size_t)HIDN * HIDN * 2);
    unsigned short* whd   = (unsigned short*)alloc((size_t)NHEAD * HIDN * 2);
    float*          accz  = (float*)alloc((size_t)(NROI * HIDN * 2 + NROI * NHEAD) * 4); // 5 MB
    unsigned short* ft0 = (unsigned short*)alloc((size_t)2 * 40000 * CCH * 2);  // 41 MB
    unsigned short* ft1 = (unsigned short*)alloc((size_t)2 * 10000 * CCH * 2);
    unsigned short* ft2 = (unsigned short*)alloc((size_t)2 * 2500 * CCH * 2);
    unsigned short* ft3 = (unsigned short*)alloc((size_t)2 * 625 * CCH * 2);
    bool nhwc = (size_t)(p - (char*)d_ws) <= ws_size;

    float* y1f = accz;
    float* y2f = accz + (size_t)NROI * HIDN;
    float* hf  = accz + (size_t)NROI * HIDN * 2;

    // prep: rois copy + zero accumulators + w2 cvt + head pack
    prep_k<<<PREP_B3, 256, 0, stream>>>(rois, w2, wc, wr, out, accz, w2b, whd);
    permute_w1_k<<<HIDN, 256, 0, stream>>>(w1, w1b);

    if (nhwc) {
        transpose_all_k<<<dim3(1662, 4, 2), 256, 0, stream>>>(p2, p3, p4, p5,
                                                              ft0, ft1, ft2, ft3);
        roi_align_k<<<dim3(POOLP, NROI), 256, 0, stream>>>(ft0, ft1, ft2, ft3, rois, xpool);
    } else {
        roi_align_nchw_k<<<dim3(POOLP, NROI), 256, 0, stream>>>(p2, p3, p4, p5, rois, xpool);
    }

    // FC1: (512,12544)x(1024,12544)^T, 128^2 tile, split-K 14, atomic acc
    gemm128_bf16_k<<<8 * 4 * KS1, 256, 0, stream>>>(
        xpool, w1b, y1f, NROI, HIDN, DDIM, DDIM / KS1);
    fc_ep_k<<<(NROI * HIDN + 255) / 256, 256, 0, stream>>>(y1f, b1, y1b, NROI * HIDN);

    // FC2: (512,1024)x(1024,1024)^T, split-K 2, atomic acc
    gemm_bf16_k<<<dim3(HIDN / 64, NROI / 64, 2), 256, 0, stream>>>(
        y1b, w2b, y2f, NROI, HIDN, HIDN, HIDN / 2);
    fc_ep_k<<<(NROI * HIDN + 255) / 256, 256, 0, stream>>>(y2f, b2, y2b, NROI * HIDN);

    // head: (512,1024)x(512,1024)^T, split-K 4, atomic acc
    gemm_bf16_k<<<dim3(NHEAD / 64, NROI / 64, 4), 256, 0, stream>>>(
        y2b, whd, hf, NROI, NHEAD, HIDN, HIDN / 4);
    head_ep_k<<<NROI, 64, 0, stream>>>(hf, bc, br, out);
}

// Round 5
// 162.128 us; speedup vs baseline: 10.3888x; 1.0064x over previous
//
#include <hip/hip_runtime.h>
#include <hip/hip_bf16.h>
#include <math.h>

// Problem constants
#define NROI   512
#define CCH    256
#define POOLP  7
#define DDIM   12544   // 256*7*7
#define HIDN   1024
#define NCLS   81
#define NREG   324
#define NHEAD  512           // padded head N: 81 cls + 324 reg + 107 pad
#define OUT_ROIS   2560      // 2*256*5
#define OUT_CLS    (512*81)

typedef __attribute__((ext_vector_type(4))) float f32x4;
typedef __attribute__((ext_vector_type(8))) short bf16x8;

static __device__ __forceinline__ unsigned short f2bf(float x) {
    __hip_bfloat16 h = __float2bfloat16(x);
    return *reinterpret_cast<unsigned short*>(&h);
}
static __device__ __forceinline__ float bf2f(unsigned short u) {
    unsigned int b = ((unsigned int)u) << 16;
    return *reinterpret_cast<float*>(&b);
}

// ---------------------------------------------------------------------------
// merged preprocess kernel, block-range dispatch:
//  [0,10)        rois copy -> out
//  [10,1290)     zero accumulators (5.24 MB)
//  [1290,2314)   w2 fp32 -> bf16
//  [2314,3338)   head weight pack (cls+reg -> padded 512x1024 bf16)
//  [3338,4362)   w1 column-permute + bf16  (k' = s*256+c from k = c*49+s)
//  [4362,17658)  NCHW fp32 -> NHWC bf16 transpose, 4 levels
#define PP_B0 10
#define PP_B1 (PP_B0 + 1280)
#define PP_B2 (PP_B1 + 1024)
#define PP_B3 (PP_B2 + 1024)
#define PP_B4 (PP_B3 + 1024)
#define PP_B5 (PP_B4 + 13296)
__global__ __launch_bounds__(256) void preprocess_k(
        const float* __restrict__ rois, const float* __restrict__ w1,
        const float* __restrict__ w2, const float* __restrict__ wc,
        const float* __restrict__ wr,
        const float* __restrict__ p2, const float* __restrict__ p3,
        const float* __restrict__ p4, const float* __restrict__ p5,
        float* __restrict__ out, float* __restrict__ accz,
        unsigned short* __restrict__ w1b, unsigned short* __restrict__ w2b,
        unsigned short* __restrict__ whd,
        unsigned short* __restrict__ f0, unsigned short* __restrict__ f1,
        unsigned short* __restrict__ f2, unsigned short* __restrict__ f3) {
    __shared__ unsigned short sm[49 * 258];   // union: permute 49x258 | transpose 32x66
    int bid = blockIdx.x, t = threadIdx.x;

    if (bid < PP_B0) {
        int i = bid * 256 + t;
        if (i < OUT_ROIS) out[i] = rois[i];
    } else if (bid < PP_B1) {
        int i = (bid - PP_B0) * 256 + t;              // float4, 327680 total
        ((float4*)accz)[i] = make_float4(0.f, 0.f, 0.f, 0.f);
    } else if (bid < PP_B2) {
        int i = (bid - PP_B1) * 256 + t;              // float4, 262144 total
        float4 v = ((const float4*)w2)[i];
        ushort4 o;
        o.x = f2bf(v.x); o.y = f2bf(v.y); o.z = f2bf(v.z); o.w = f2bf(v.w);
        ((ushort4*)w2b)[i] = o;
    } else if (bid < PP_B3) {
        int i2 = (bid - PP_B2) * 256 + t;             // ushort2, 262144 total
        int r = i2 >> 9, c = (i2 & 511) << 1;
        float v0, v1;
        if (r < NCLS)             { v0 = wc[r * HIDN + c]; v1 = wc[r * HIDN + c + 1]; }
        else if (r < NCLS + NREG) { v0 = wr[(r - NCLS) * HIDN + c]; v1 = wr[(r - NCLS) * HIDN + c + 1]; }
        else                      { v0 = 0.f; v1 = 0.f; }
        ((unsigned int*)whd)[i2] = (unsigned int)f2bf(v0) | ((unsigned int)f2bf(v1) << 16);
    } else if (bid < PP_B4) {
        // w1 permute: w1b[n][s*256+c] = w1[n][c*49+s]
        int n = bid - PP_B3;
        const float* src = w1 + (size_t)n * DDIM;
        for (int k = t; k < DDIM; k += 256) {
            int c = k / 49;
            int s = k - c * 49;
            sm[s * 258 + c] = f2bf(src[k]);
        }
        __syncthreads();
        unsigned int* dst = (unsigned int*)(w1b + (size_t)n * DDIM);
        for (int j2 = t; j2 < DDIM / 2; j2 += 256) {
            int s = j2 >> 7, c2 = (j2 & 127) << 1;
            dst[j2] = sm[s * 258 + c2] | ((unsigned int)sm[s * 258 + c2 + 1] << 16);
        }
    } else {
        // transpose: 32 s x 64 c tile
        int j  = bid - PP_B4;                          // 0..13295
        int xb = j % 1662;
        int q  = j / 1662;                             // 0..7
        int c0 = (q & 3) * 64;
        int b  = q >> 2;
        const float* in; unsigned short* op; int S, base;
        if (xb < 1250)      { in = p2; op = f0; S = 40000; base = 0; }
        else if (xb < 1563) { in = p3; op = f1; S = 10000; base = 1250; }
        else if (xb < 1642) { in = p4; op = f2; S = 2500;  base = 1563; }
        else                { in = p5; op = f3; S = 625;   base = 1642; }
        int s0 = (xb - base) * 32;
        {
            int sL = t & 31, cq = t >> 5;
            const float* src = in + ((size_t)b * CCH + c0 + cq * 8) * S + s0 + sL;
            bool ok = (s0 + sL) < S;
#pragma unroll
            for (int jj = 0; jj < 8; jj++)
                sm[sL * 66 + cq * 8 + jj] = ok ? f2bf(src[(size_t)jj * S]) : (unsigned short)0;
        }
        __syncthreads();
        {
            int c2 = t & 31, sq = t >> 5;
#pragma unroll
            for (int i = 0; i < 4; i++) {
                int s = sq * 4 + i;
                if (s0 + s < S) {
                    unsigned int v = sm[s * 66 + c2 * 2]
                                   | ((unsigned int)sm[s * 66 + c2 * 2 + 1] << 16);
                    ((unsigned int*)(op + ((size_t)b * S + s0 + s) * CCH + c0))[c2] = v;
                }
            }
        }
    }
}

// ---------------------------------------------------------------------------
// ROI Align, block per (py, roi), 256 threads = channels, bf16 NHWC features.
// xpool[r][ (py*7+px)*256 + c ]  (k-permuted layout, matches w1 permute)
__global__ __launch_bounds__(256) void roi_align_k(const unsigned short* __restrict__ f0,
                                                   const unsigned short* __restrict__ f1,
                                                   const unsigned short* __restrict__ f2,
                                                   const unsigned short* __restrict__ f3,
                                                   const float* __restrict__ rois,
                                                   unsigned short* __restrict__ xpool) {
    __shared__ float s_f[16];
    __shared__ int   s_lo[16], s_hi[16], s_v[16];

    int py = blockIdx.x, r = blockIdx.y, t = threadIdx.x;

    float r0  = rois[r * 5 + 0];
    float rx1 = rois[r * 5 + 1], ry1 = rois[r * 5 + 2];
    float rx2 = rois[r * 5 + 3], ry2 = rois[r * 5 + 4];
    int b = (int)r0;

    float aw = rx2 - rx1 + 1.f, ah = ry2 - ry1 + 1.f;
    float lvf = floorf(log2f(sqrtf(ah * aw) / 56.f + 1e-6f));
    int lv = (int)fminf(fmaxf(lvf, 0.f), 3.f);

    const unsigned short* F = (lv == 0) ? f0 : (lv == 1) ? f1 : (lv == 2) ? f2 : f3;
    int HW      = (lv == 0) ? 200 : (lv == 1) ? 100 : (lv == 2) ? 50 : 25;
    float scale = (lv == 0) ? 0.25f : (lv == 1) ? 0.125f : (lv == 2) ? 0.0625f : 0.03125f;

    float x1 = rx1 * scale, yy1 = ry1 * scale;
    float x2 = rx2 * scale, yy2 = ry2 * scale;
    float rw = fmaxf(x2 - x1, 1.f), rh = fmaxf(yy2 - yy1, 1.f);

    if (t < 16) {
        bool isY = t < 2;
        float coord;
        if (isY) {
            float g = (float)py + ((float)t + 0.5f) * 0.5f;
            coord = yy1 + g * (rh * (1.f / 7.f));
        } else {
            int j = t - 2;
            float g = (float)(j >> 1) + ((float)(j & 1) + 0.5f) * 0.5f;
            coord = x1 + g * (rw * (1.f / 7.f));
        }
        int vld = (coord >= -1.f && coord <= (float)HW) ? 1 : 0;
        float c = fminf(fmaxf(coord, 0.f), (float)(HW - 1));
        int lo  = (int)floorf(c);
        int hi  = min(lo + 1, HW - 1);
        s_v[t] = vld; s_lo[t] = lo; s_hi[t] = hi; s_f[t] = c - (float)lo;
    }
    __syncthreads();

    const unsigned short* Fb = F + ((size_t)b * HW * HW) * CCH + t;
    size_t obase = (size_t)r * DDIM + py * 7 * 256 + t;

    for (int px = 0; px < POOLP; px++) {
        float acc = 0.f;
#pragma unroll
        for (int s = 0; s < 4; s++) {
            int iy = s >> 1;
            int ix = px * 2 + (s & 1);
            int vy = s_v[iy], vx = s_v[2 + ix];
            if (vy & vx) {
                float fy = s_f[iy], fx = s_f[2 + ix];
                int ylo = s_lo[iy], yhi = s_hi[iy];
                int xlo = s_lo[2 + ix], xhi = s_hi[2 + ix];
                float v00 = bf2f(Fb[((size_t)ylo * HW + xlo) * CCH]);
                float v01 = bf2f(Fb[((size_t)ylo * HW + xhi) * CCH]);
                float v10 = bf2f(Fb[((size_t)yhi * HW + xlo) * CCH]);
                float v11 = bf2f(Fb[((size_t)yhi * HW + xhi) * CCH]);
                acc += (1.f - fy) * ((1.f - fx) * v00 + fx * v01)
                     + fy * ((1.f - fx) * v10 + fx * v11);
            }
        }
        xpool[obase + px * 256] = f2bf(acc * 0.25f);
    }
}

// NCHW fp32 fallback (only if ws too small for NHWC staging)
__global__ __launch_bounds__(256) void roi_align_nchw_k(const float* __restrict__ f0,
                                                        const float* __restrict__ f1,
                                                        const float* __restrict__ f2,
                                                        const float* __restrict__ f3,
                                                        const float* __restrict__ rois,
                                                        unsigned short* __restrict__ xpool) {
    __shared__ float s_f[16];
    __shared__ int   s_lo[16], s_hi[16], s_v[16];
    int py = blockIdx.x, r = blockIdx.y, t = threadIdx.x;
    float r0  = rois[r * 5 + 0];
    float rx1 = rois[r * 5 + 1], ry1 = rois[r * 5 + 2];
    float rx2 = rois[r * 5 + 3], ry2 = rois[r * 5 + 4];
    int b = (int)r0;
    float aw = rx2 - rx1 + 1.f, ah = ry2 - ry1 + 1.f;
    float lvf = floorf(log2f(sqrtf(ah * aw) / 56.f + 1e-6f));
    int lv = (int)fminf(fmaxf(lvf, 0.f), 3.f);
    const float* F = (lv == 0) ? f0 : (lv == 1) ? f1 : (lv == 2) ? f2 : f3;
    int HW      = (lv == 0) ? 200 : (lv == 1) ? 100 : (lv == 2) ? 50 : 25;
    float scale = (lv == 0) ? 0.25f : (lv == 1) ? 0.125f : (lv == 2) ? 0.0625f : 0.03125f;
    float x1 = rx1 * scale, yy1 = ry1 * scale;
    float x2 = rx2 * scale, yy2 = ry2 * scale;
    float rw = fmaxf(x2 - x1, 1.f), rh = fmaxf(yy2 - yy1, 1.f);
    if (t < 16) {
        bool isY = t < 2;
        float coord;
        if (isY) {
            float g = (float)py + ((float)t + 0.5f) * 0.5f;
            coord = yy1 + g * (rh * (1.f / 7.f));
        } else {
            int j = t - 2;
            float g = (float)(j >> 1) + ((float)(j & 1) + 0.5f) * 0.5f;
            coord = x1 + g * (rw * (1.f / 7.f));
        }
        int vld = (coord >= -1.f && coord <= (float)HW) ? 1 : 0;
        float c = fminf(fmaxf(coord, 0.f), (float)(HW - 1));
        int lo  = (int)floorf(c);
        int hi  = min(lo + 1, HW - 1);
        s_v[t] = vld; s_lo[t] = lo; s_hi[t] = hi; s_f[t] = c - (float)lo;
    }
    __syncthreads();
    const float* Fb = F + ((size_t)b * CCH + t) * HW * HW;
    size_t obase = (size_t)r * DDIM + py * 7 * 256 + t;
    for (int px = 0; px < POOLP; px++) {
        float acc = 0.f;
#pragma unroll
        for (int s = 0; s < 4; s++) {
            int iy = s >> 1, ix = px * 2 + (s & 1);
            int vy = s_v[iy], vx = s_v[2 + ix];
            if (vy & vx) {
                float fy = s_f[iy], fx = s_f[2 + ix];
                int ylo = s_lo[iy], yhi = s_hi[iy];
                int xlo = s_lo[2 + ix], xhi = s_hi[2 + ix];
                float v00 = Fb[(size_t)ylo * HW + xlo];
                float v01 = Fb[(size_t)ylo * HW + xhi];
                float v10 = Fb[(size_t)yhi * HW + xlo];
                float v11 = Fb[(size_t)yhi * HW + xhi];
                acc += (1.f - fy) * ((1.f - fx) * v00 + fx * v01)
                     + fy * ((1.f - fx) * v10 + fx * v11);
            }
        }
        xpool[obase + px * 256] = f2bf(acc * 0.25f);
    }
}

// ---------------------------------------------------------------------------
// 64x64 bf16 MFMA GEMM, double-buffered 2-phase, atomic split-K (FC2/head).
__global__ __launch_bounds__(256) void gemm_bf16_k(const unsigned short* __restrict__ A,
                                                   const unsigned short* __restrict__ W,
                                                   float* __restrict__ Cacc,
                                                   int M, int N, int K, int kchunk) {
    __shared__ __align__(16) unsigned short As[2][8][64][8];
    __shared__ __align__(16) unsigned short Ws[2][8][64][8];

    int t = threadIdx.x;
    int lane = t & 63, wid = t >> 6;
    int m0 = blockIdx.y * 64, n0 = blockIdx.x * 64;
    int k0 = blockIdx.z * kchunk;
    int wm = (wid >> 1) * 32, wn = (wid & 1) * 32;
    int fr = lane & 15, kg = lane >> 4;
    int nsteps = kchunk >> 6;

    f32x4 acc[2][2] = {};

    const unsigned short* Arow = A + (size_t)(m0 + lane) * K;
    const unsigned short* Wrow = W + (size_t)(n0 + lane) * K;

    auto stage = [&](int buf, int kb) {
#pragma unroll
        for (int i = 0; i < 2; i++) {
            int c = wid * 2 + i;
            __builtin_amdgcn_global_load_lds(
                (const __attribute__((address_space(1))) void*)(Arow + kb + c * 8),
                (__attribute__((address_space(3))) void*)(&As[buf][c][0][0]), 16, 0, 0);
            __builtin_amdgcn_global_load_lds(
                (const __attribute__((address_space(1))) void*)(Wrow + kb + c * 8),
                (__attribute__((address_space(3))) void*)(&Ws[buf][c][0][0]), 16, 0, 0);
        }
    };

    stage(0, k0);
    __syncthreads();
    int cur = 0;
    for (int tt = 0; tt < nsteps; ++tt) {
        if (tt + 1 < nsteps) stage(cur ^ 1, k0 + (tt + 1) * 64);
#pragma unroll
        for (int h = 0; h < 2; h++) {
            bf16x8 a0 = *(const bf16x8*)(&As[cur][h * 4 + kg][wm + fr][0]);
            bf16x8 a1 = *(const bf16x8*)(&As[cur][h * 4 + kg][wm + 16 + fr][0]);
            bf16x8 b0 = *(const bf16x8*)(&Ws[cur][h * 4 + kg][wn + fr][0]);
            bf16x8 b1 = *(const bf16x8*)(&Ws[cur][h * 4 + kg][wn + 16 + fr][0]);
            acc[0][0] = __builtin_amdgcn_mfma_f32_16x16x32_bf16(a0, b0, acc[0][0], 0, 0, 0);
            acc[0][1] = __builtin_amdgcn_mfma_f32_16x16x32_bf16(a0, b1, acc[0][1], 0, 0, 0);
            acc[1][0] = __builtin_amdgcn_mfma_f32_16x16x32_bf16(a1, b0, acc[1][0], 0, 0, 0);
            acc[1][1] = __builtin_amdgcn_mfma_f32_16x16x32_bf16(a1, b1, acc[1][1], 0, 0, 0);
        }
        __syncthreads();
        cur ^= 1;
    }

    int row = m0 + wm + (lane >> 4) * 4;
    int col = n0 + wn + fr;
#pragma unroll
    for (int fm = 0; fm < 2; fm++)
#pragma unroll
        for (int fn = 0; fn < 2; fn++)
#pragma unroll
            for (int r = 0; r < 4; r++)
                atomicAdd(&Cacc[(size_t)(row + fm * 16 + r) * N + col + fn * 16],
                          acc[fm][fn][r]);
}

// ---------------------------------------------------------------------------
// 128x128 bf16 MFMA GEMM (FC1), dbuf 2-phase, z-innermost XCD swizzle so all
// 14 split-K blocks of one C-tile share one XCD (L2-local atomics) and the 56
// blocks of an XCD share one 3.2 MB A-panel. grid = 448 linear blocks.
__global__ __launch_bounds__(256) void gemm128_bf16_k(const unsigned short* __restrict__ A,
                                                      const unsigned short* __restrict__ W,
                                                      float* __restrict__ Cacc,
                                                      int M, int N, int K, int kchunk) {
    __shared__ __align__(16) unsigned short As[2][8][128][8];   // 2 x 16 KB
    __shared__ __align__(16) unsigned short Ws[2][8][128][8];

    int lin  = blockIdx.x;
    int nb   = (lin & 7) * 56 + (lin >> 3);   // 448 = 8 XCD x 56, bijective
    int tile = nb / 14, bz = nb - tile * 14;  // nb = tile*14 + z  (z innermost)
    int bx = tile & 7, by = tile >> 3;

    int t = threadIdx.x;
    int lane = t & 63, wid = t >> 6;
    int m0 = by * 128, n0 = bx * 128;
    int k0 = bz * kchunk;
    int wm = (wid >> 1) * 64, wn = (wid & 1) * 64;
    int fr = lane & 15, kg = lane >> 4;
    int nsteps = kchunk >> 6;

    f32x4 acc[4][4] = {};

    auto stage = [&](int buf, int kb) {
#pragma unroll
        for (int i = 0; i < 4; i++) {
            int c   = wid * 4 + i;
            int kgc = c >> 1;
            int r0w = (c & 1) * 64;
            __builtin_amdgcn_global_load_lds(
                (const __attribute__((address_space(1))) void*)
                    (A + (size_t)(m0 + r0w + lane) * K + kb + kgc * 8),
                (__attribute__((address_space(3))) void*)(&As[buf][kgc][r0w][0]), 16, 0, 0);
            __builtin_amdgcn_global_load_lds(
                (const __attribute__((address_space(1))) void*)
                    (W + (size_t)(n0 + r0w + lane) * K + kb + kgc * 8),
                (__attribute__((address_space(3))) void*)(&Ws[buf][kgc][r0w][0]), 16, 0, 0);
        }
    };

    stage(0, k0);
    __syncthreads();
    int cur = 0;
    for (int tt = 0; tt < nsteps; ++tt) {
        if (tt + 1 < nsteps) stage(cur ^ 1, k0 + (tt + 1) * 64);
#pragma unroll
        for (int h = 0; h < 2; h++) {
            bf16x8 av[4], bv[4];
#pragma unroll
            for (int f = 0; f < 4; f++) {
                av[f] = *(const bf16x8*)(&As[cur][h * 4 + kg][wm + f * 16 + fr][0]);
                bv[f] = *(const bf16x8*)(&Ws[cur][h * 4 + kg][wn + f * 16 + fr][0]);
            }
#pragma unroll
            for (int fm = 0; fm < 4; fm++)
#pragma unroll
                for (int fn = 0; fn < 4; fn++)
                    acc[fm][fn] = __builtin_amdgcn_mfma_f32_16x16x32_bf16(
                        av[fm], bv[fn], acc[fm][fn], 0, 0, 0);
        }
        __syncthreads();
        cur ^= 1;
    }

    int row = m0 + wm + (lane >> 4) * 4;
    int col = n0 + wn + fr;
#pragma unroll
    for (int fm = 0; fm < 4; fm++)
#pragma unroll
        for (int fn = 0; fn < 4; fn++)
#pragma unroll
            for (int r = 0; r < 4; r++)
                atomicAdd(&Cacc[(size_t)(row + fm * 16 + r) * N + col + fn * 16],
                          acc[fm][fn][r]);
}

// ---------------------------------------------------------------------------
// fp32 accumulator + bias -> relu -> bf16  (N == HIDN)
__global__ __launch_bounds__(256) void fc_ep_k(const float* __restrict__ acc,
                                               const float* __restrict__ bias,
                                               unsigned short* __restrict__ dst, int MN) {
    int i = blockIdx.x * 256 + threadIdx.x;
    if (i >= MN) return;
    float s = fmaxf(acc[i] + bias[i & (HIDN - 1)], 0.f);
    dst[i] = f2bf(s);
}

// head accumulator (512x512) -> bias + reg out + softmax(cls) out. Block = roi.
__global__ void head_ep_k(const float* __restrict__ hf,
                          const float* __restrict__ bc,
                          const float* __restrict__ br,
                          float* __restrict__ out) {
    int r = blockIdx.x, l = threadIdx.x;   // 64 threads
    const float* row = hf + (size_t)r * NHEAD;

    float* reg = out + OUT_ROIS + OUT_CLS + (size_t)r * NREG;
    for (int j = l; j < NREG; j += 64) reg[j] = row[NCLS + j] + br[j];

    float v0 = row[l] + bc[l];
    float v1 = (l + 64 < NCLS) ? row[l + 64] + bc[l + 64] : -INFINITY;
    float m = fmaxf(v0, v1);
#pragma unroll
    for (int o = 32; o; o >>= 1) m = fmaxf(m, __shfl_xor(m, o));
    float e0 = __expf(v0 - m);
    float e1 = (l + 64 < NCLS) ? __expf(v1 - m) : 0.f;
    float s = e0 + e1;
#pragma unroll
    for (int o = 32; o; o >>= 1) s += __shfl_xor(s, o);
    float inv = 1.f / s;
    float* cls = out + OUT_ROIS + (size_t)r * NCLS;
    cls[l] = e0 * inv;
    if (l + 64 < NCLS) cls[l + 64] = e1 * inv;
}

// ---------------------------------------------------------------------------
extern "C" void kernel_launch(void* const* d_in, const int* in_sizes, int n_in,
                              void* d_out, int out_size, void* d_ws, size_t ws_size,
                              hipStream_t stream) {
    const float* p2   = (const float*)d_in[0];
    const float* p3   = (const float*)d_in[1];
    const float* p4   = (const float*)d_in[2];
    const float* p5   = (const float*)d_in[3];
    const float* rois = (const float*)d_in[4];
    const float* w1   = (const float*)d_in[5];
    const float* b1   = (const float*)d_in[6];
    const float* w2   = (const float*)d_in[7];
    const float* b2   = (const float*)d_in[8];
    const float* wc   = (const float*)d_in[9];
    const float* bc   = (const float*)d_in[10];
    const float* wr   = (const float*)d_in[11];
    const float* br   = (const float*)d_in[12];

    float* out = (float*)d_out;

    const int KS1 = 14;   // FC1 split-K (12544 = 14 * 896)

    // workspace carve-up (256B-aligned chunks)
    char* p = (char*)d_ws;
    auto alloc = [&](size_t bytes) { char* r = p; p += (bytes + 255) & ~(size_t)255; return r; };
    unsigned short* xpool = (unsigned short*)alloc((size_t)NROI * DDIM * 2);    // 12.8 MB
    unsigned short* y1b   = (unsigned short*)alloc((size_t)NROI * HIDN * 2);
    unsigned short* y2b   = (unsigned short*)alloc((size_t)NROI * HIDN * 2);
    unsigned short* w1b   = (unsigned short*)alloc((size_t)HIDN * DDIM * 2);    // 25.7 MB
    unsigned short* w2b   = (unsigned short*)alloc((size_t)HIDN * HIDN * 2);
    unsigned short* whd   = (unsigned short*)alloc((size_t)NHEAD * HIDN * 2);
    float*          accz  = (float*)alloc((size_t)(NROI * HIDN * 2 + NROI * NHEAD) * 4); // 5.24 MB
    unsigned short* ft0 = (unsigned short*)alloc((size_t)2 * 40000 * CCH * 2);  // 41 MB
    unsigned short* ft1 = (unsigned short*)alloc((size_t)2 * 10000 * CCH * 2);
    unsigned short* ft2 = (unsigned short*)alloc((size_t)2 * 2500 * CCH * 2);
    unsigned short* ft3 = (unsigned short*)alloc((size_t)2 * 625 * CCH * 2);
    bool nhwc = (size_t)(p - (char*)d_ws) <= ws_size;

    float* y1f = accz;
    float* y2f = accz + (size_t)NROI * HIDN;
    float* hf  = accz + (size_t)NROI * HIDN * 2;

    // preprocess: rois copy + zero acc + w2 cvt + head pack + w1 permute [+ transpose]
    preprocess_k<<<nhwc ? PP_B5 : PP_B4, 256, 0, stream>>>(
        rois, w1, w2, wc, wr, p2, p3, p4, p5,
        out, accz, w1b, w2b, whd, ft0, ft1, ft2, ft3);

    if (nhwc) {
        roi_align_k<<<dim3(POOLP, NROI), 256, 0, stream>>>(ft0, ft1, ft2, ft3, rois, xpool);
    } else {
        roi_align_nchw_k<<<dim3(POOLP, NROI), 256, 0, stream>>>(p2, p3, p4, p5, rois, xpool);
    }

    // FC1: (512,12544)x(1024,12544)^T, 128^2 tile, split-K 14, atomic acc
    gemm128_bf16_k<<<8 * 4 * KS1, 256, 0, stream>>>(
        xpool, w1b, y1f, NROI, HIDN, DDIM, DDIM / KS1);
    fc_ep_k<<<(NROI * HIDN + 255) / 256, 256, 0, stream>>>(y1f, b1, y1b, NROI * HIDN);

    // FC2: (512,1024)x(1024,1024)^T, split-K 2, atomic acc
    gemm_bf16_k<<<dim3(HIDN / 64, NROI / 64, 2), 256, 0, stream>>>(
        y1b, w2b, y2f, NROI, HIDN, HIDN, HIDN / 2);
    fc_ep_k<<<(NROI * HIDN + 255) / 256, 256, 0, stream>>>(y2f, b2, y2b, NROI * HIDN);

    // head: (512,1024)x(512,1024)^T, split-K 4, atomic acc
    gemm_bf16_k<<<dim3(NHEAD / 64, NROI / 64, 4), 256, 0, stream>>>(
        y2b, whd, hf, NROI, NHEAD, HIDN, HIDN / 4);
    head_ep_k<<<NROI, 64, 0, stream>>>(hf, bc, br, out);
}

// Round 6
// 156.847 us; speedup vs baseline: 10.7385x; 1.0337x over previous
//
#include <hip/hip_runtime.h>
#include <hip/hip_bf16.h>
#include <math.h>

// Problem constants
#define NROI   512
#define CCH    256
#define POOLP  7
#define DDIM   12544   // 256*7*7
#define HIDN   1024
#define NCLS   81
#define NREG   324
#define NHEAD  512           // padded head N: 81 cls + 324 reg + 107 pad
#define OUT_ROIS   2560      // 2*256*5
#define OUT_CLS    (512*81)

typedef __attribute__((ext_vector_type(4))) float f32x4;
typedef __attribute__((ext_vector_type(8))) short bf16x8;

static __device__ __forceinline__ unsigned short f2bf(float x) {
    __hip_bfloat16 h = __float2bfloat16(x);
    return *reinterpret_cast<unsigned short*>(&h);
}
static __device__ __forceinline__ float bf2f(unsigned short u) {
    unsigned int b = ((unsigned int)u) << 16;
    return *reinterpret_cast<float*>(&b);
}

// ---------------------------------------------------------------------------
// prep_small: [0,10) rois | [10,778) zero acc (3.1MB) | [778,1802) w2 cvt
//             | [1802,2826) head pack
#define PS_B0 10
#define PS_B1 (PS_B0 + 768)
#define PS_B2 (PS_B1 + 1024)
#define PS_B3 (PS_B2 + 1024)
__global__ __launch_bounds__(256) void prep_small_k(const float* __restrict__ rois,
                                                    const float* __restrict__ w2,
                                                    const float* __restrict__ wc,
                                                    const float* __restrict__ wr,
                                                    float* __restrict__ out,
                                                    float* __restrict__ accz,
                                                    unsigned short* __restrict__ w2b,
                                                    unsigned short* __restrict__ whd) {
    int bid = blockIdx.x, t = threadIdx.x;
    if (bid < PS_B0) {
        int i = bid * 256 + t;
        if (i < OUT_ROIS) out[i] = rois[i];
    } else if (bid < PS_B1) {
        int i = (bid - PS_B0) * 256 + t;              // float4, 196608 total
        ((float4*)accz)[i] = make_float4(0.f, 0.f, 0.f, 0.f);
    } else if (bid < PS_B2) {
        int i = (bid - PS_B1) * 256 + t;              // float4, 262144 total
        float4 v = ((const float4*)w2)[i];
        ushort4 o;
        o.x = f2bf(v.x); o.y = f2bf(v.y); o.z = f2bf(v.z); o.w = f2bf(v.w);
        ((ushort4*)w2b)[i] = o;
    } else {
        int i2 = (bid - PS_B2) * 256 + t;             // ushort2, 262144 total
        int r = i2 >> 9, c = (i2 & 511) << 1;
        float v0, v1;
        if (r < NCLS)             { v0 = wc[r * HIDN + c]; v1 = wc[r * HIDN + c + 1]; }
        else if (r < NCLS + NREG) { v0 = wr[(r - NCLS) * HIDN + c]; v1 = wr[(r - NCLS) * HIDN + c + 1]; }
        else                      { v0 = 0.f; v1 = 0.f; }
        ((unsigned int*)whd)[i2] = (unsigned int)f2bf(v0) | ((unsigned int)f2bf(v1) << 16);
    }
}

// ---------------------------------------------------------------------------
// w1 column-permute + bf16: w1b[n][s*256+c] = w1[n][c*49+s]  (s=py*7+px)
__global__ __launch_bounds__(256) void permute_w1_k(const float* __restrict__ w1,
                                                    unsigned short* __restrict__ w1b) {
    __shared__ unsigned short lw[49 * 258];
    int n = blockIdx.x, t = threadIdx.x;
    const float* src = w1 + (size_t)n * DDIM;
    for (int k = t; k < DDIM; k += 256) {
        int c = k / 49;
        int s = k - c * 49;
        lw[s * 258 + c] = f2bf(src[k]);
    }
    __syncthreads();
    unsigned int* dst = (unsigned int*)(w1b + (size_t)n * DDIM);
    for (int j2 = t; j2 < DDIM / 2; j2 += 256) {
        int s = j2 >> 7, c2 = (j2 & 127) << 1;
        dst[j2] = lw[s * 258 + c2] | ((unsigned int)lw[s * 258 + c2 + 1] << 16);
    }
}

// ---------------------------------------------------------------------------
// NCHW fp32 -> NHWC bf16 transpose, 64s x 64c tile, float4 reads, uint2 writes.
// x-block = s-tile: [0,625) p2 | [625,782) p3 | [782,822) p4 | [822,832) p5
__global__ __launch_bounds__(256) void transpose_k(const float* __restrict__ p2,
                                                   const float* __restrict__ p3,
                                                   const float* __restrict__ p4,
                                                   const float* __restrict__ p5,
                                                   unsigned short* __restrict__ f0,
                                                   unsigned short* __restrict__ f1,
                                                   unsigned short* __restrict__ f2,
                                                   unsigned short* __restrict__ f3) {
    __shared__ float sm[64][65];
    int xb = blockIdx.x;
    const float* in; unsigned short* op; int S, base;
    if (xb < 625)      { in = p2; op = f0; S = 40000; base = 0; }
    else if (xb < 782) { in = p3; op = f1; S = 10000; base = 625; }
    else if (xb < 822) { in = p4; op = f2; S = 2500;  base = 782; }
    else               { in = p5; op = f3; S = 625;   base = 822; }
    int s0 = (xb - base) * 64;
    int c0 = blockIdx.y * 64;
    int b  = blockIdx.z;
    int t  = threadIdx.x;

    int sL = (t & 15) * 4, cc0 = t >> 4;
    // float4 path needs 16B-aligned rows: S%4==0 (p5's S=625 uses scalar path)
    bool vec = (s0 + 64 <= S) && ((S & 3) == 0);
#pragma unroll
    for (int i = 0; i < 4; i++) {
        int cc = cc0 + i * 16;
        const float* src = in + ((size_t)(b * CCH + c0 + cc)) * S + s0 + sL;
        if (vec) {
            float4 v = *(const float4*)src;
            sm[sL + 0][cc] = v.x; sm[sL + 1][cc] = v.y;
            sm[sL + 2][cc] = v.z; sm[sL + 3][cc] = v.w;
        } else {
#pragma unroll
            for (int j = 0; j < 4; j++)
                sm[sL + j][cc] = (s0 + sL + j < S) ? src[j] : 0.f;
        }
    }
    __syncthreads();

    int cq = (t & 15) * 4, sr = t >> 4;
#pragma unroll
    for (int i = 0; i < 4; i++) {
        int s = sr + i * 16;
        if (s0 + s < S) {
            float a = sm[s][cq], bb = sm[s][cq + 1], c = sm[s][cq + 2], d = sm[s][cq + 3];
            uint2 v;
            v.x = (unsigned int)f2bf(a) | ((unsigned int)f2bf(bb) << 16);
            v.y = (unsigned int)f2bf(c) | ((unsigned int)f2bf(d) << 16);
            *(uint2*)(op + ((size_t)b * S + s0 + s) * CCH + c0 + cq) = v;
        }
    }
}

// ---------------------------------------------------------------------------
// ROI Align, block per (py, roi), 256 threads = channels, bf16 NHWC features.
// xpool[r][ (py*7+px)*256 + c ]  (k-permuted layout, matches w1 permute)
__global__ __launch_bounds__(256) void roi_align_k(const unsigned short* __restrict__ f0,
                                                   const unsigned short* __restrict__ f1,
                                                   const unsigned short* __restrict__ f2,
                                                   const unsigned short* __restrict__ f3,
                                                   const float* __restrict__ rois,
                                                   unsigned short* __restrict__ xpool) {
    __shared__ float s_f[16];
    __shared__ int   s_lo[16], s_hi[16], s_v[16];

    int py = blockIdx.x, r = blockIdx.y, t = threadIdx.x;

    float r0  = rois[r * 5 + 0];
    float rx1 = rois[r * 5 + 1], ry1 = rois[r * 5 + 2];
    float rx2 = rois[r * 5 + 3], ry2 = rois[r * 5 + 4];
    int b = (int)r0;

    float aw = rx2 - rx1 + 1.f, ah = ry2 - ry1 + 1.f;
    float lvf = floorf(log2f(sqrtf(ah * aw) / 56.f + 1e-6f));
    int lv = (int)fminf(fmaxf(lvf, 0.f), 3.f);

    const unsigned short* F = (lv == 0) ? f0 : (lv == 1) ? f1 : (lv == 2) ? f2 : f3;
    int HW      = (lv == 0) ? 200 : (lv == 1) ? 100 : (lv == 2) ? 50 : 25;
    float scale = (lv == 0) ? 0.25f : (lv == 1) ? 0.125f : (lv == 2) ? 0.0625f : 0.03125f;

    float x1 = rx1 * scale, yy1 = ry1 * scale;
    float x2 = rx2 * scale, yy2 = ry2 * scale;
    float rw = fmaxf(x2 - x1, 1.f), rh = fmaxf(yy2 - yy1, 1.f);

    if (t < 16) {
        bool isY = t < 2;
        float coord;
        if (isY) {
            float g = (float)py + ((float)t + 0.5f) * 0.5f;
            coord = yy1 + g * (rh * (1.f / 7.f));
        } else {
            int j = t - 2;
            float g = (float)(j >> 1) + ((float)(j & 1) + 0.5f) * 0.5f;
            coord = x1 + g * (rw * (1.f / 7.f));
        }
        int vld = (coord >= -1.f && coord <= (float)HW) ? 1 : 0;
        float c = fminf(fmaxf(coord, 0.f), (float)(HW - 1));
        int lo  = (int)floorf(c);
        int hi  = min(lo + 1, HW - 1);
        s_v[t] = vld; s_lo[t] = lo; s_hi[t] = hi; s_f[t] = c - (float)lo;
    }
    __syncthreads();

    const unsigned short* Fb = F + ((size_t)b * HW * HW) * CCH + t;
    size_t obase = (size_t)r * DDIM + py * 7 * 256 + t;

    for (int px = 0; px < POOLP; px++) {
        float acc = 0.f;
#pragma unroll
        for (int s = 0; s < 4; s++) {
            int iy = s >> 1;
            int ix = px * 2 + (s & 1);
            int vy = s_v[iy], vx = s_v[2 + ix];
            if (vy & vx) {
                float fy = s_f[iy], fx = s_f[2 + ix];
                int ylo = s_lo[iy], yhi = s_hi[iy];
                int xlo = s_lo[2 + ix], xhi = s_hi[2 + ix];
                float v00 = bf2f(Fb[((size_t)ylo * HW + xlo) * CCH]);
                float v01 = bf2f(Fb[((size_t)ylo * HW + xhi) * CCH]);
                float v10 = bf2f(Fb[((size_t)yhi * HW + xlo) * CCH]);
                float v11 = bf2f(Fb[((size_t)yhi * HW + xhi) * CCH]);
                acc += (1.f - fy) * ((1.f - fx) * v00 + fx * v01)
                     + fy * ((1.f - fx) * v10 + fx * v11);
            }
        }
        xpool[obase + px * 256] = f2bf(acc * 0.25f);
    }
}

// NCHW fp32 fallback (only if ws too small for NHWC staging)
__global__ __launch_bounds__(256) void roi_align_nchw_k(const float* __restrict__ f0,
                                                        const float* __restrict__ f1,
                                                        const float* __restrict__ f2,
                                                        const float* __restrict__ f3,
                                                        const float* __restrict__ rois,
                                                        unsigned short* __restrict__ xpool) {
    __shared__ float s_f[16];
    __shared__ int   s_lo[16], s_hi[16], s_v[16];
    int py = blockIdx.x, r = blockIdx.y, t = threadIdx.x;
    float r0  = rois[r * 5 + 0];
    float rx1 = rois[r * 5 + 1], ry1 = rois[r * 5 + 2];
    float rx2 = rois[r * 5 + 3], ry2 = rois[r * 5 + 4];
    int b = (int)r0;
    float aw = rx2 - rx1 + 1.f, ah = ry2 - ry1 + 1.f;
    float lvf = floorf(log2f(sqrtf(ah * aw) / 56.f + 1e-6f));
    int lv = (int)fminf(fmaxf(lvf, 0.f), 3.f);
    const float* F = (lv == 0) ? f0 : (lv == 1) ? f1 : (lv == 2) ? f2 : f3;
    int HW      = (lv == 0) ? 200 : (lv == 1) ? 100 : (lv == 2) ? 50 : 25;
    float scale = (lv == 0) ? 0.25f : (lv == 1) ? 0.125f : (lv == 2) ? 0.0625f : 0.03125f;
    float x1 = rx1 * scale, yy1 = ry1 * scale;
    float x2 = rx2 * scale, yy2 = ry2 * scale;
    float rw = fmaxf(x2 - x1, 1.f), rh = fmaxf(yy2 - yy1, 1.f);
    if (t < 16) {
        bool isY = t < 2;
        float coord;
        if (isY) {
            float g = (float)py + ((float)t + 0.5f) * 0.5f;
            coord = yy1 + g * (rh * (1.f / 7.f));
        } else {
            int j = t - 2;
            float g = (float)(j >> 1) + ((float)(j & 1) + 0.5f) * 0.5f;
            coord = x1 + g * (rw * (1.f / 7.f));
        }
        int vld = (coord >= -1.f && coord <= (float)HW) ? 1 : 0;
        float c = fminf(fmaxf(coord, 0.f), (float)(HW - 1));
        int lo  = (int)floorf(c);
        int hi  = min(lo + 1, HW - 1);
        s_v[t] = vld; s_lo[t] = lo; s_hi[t] = hi; s_f[t] = c - (float)lo;
    }
    __syncthreads();
    const float* Fb = F + ((size_t)b * CCH + t) * HW * HW;
    size_t obase = (size_t)r * DDIM + py * 7 * 256 + t;
    for (int px = 0; px < POOLP; px++) {
        float acc = 0.f;
#pragma unroll
        for (int s = 0; s < 4; s++) {
            int iy = s >> 1, ix = px * 2 + (s & 1);
            int vy = s_v[iy], vx = s_v[2 + ix];
            if (vy & vx) {
                float fy = s_f[iy], fx = s_f[2 + ix];
                int ylo = s_lo[iy], yhi = s_hi[iy];
                int xlo = s_lo[2 + ix], xhi = s_hi[2 + ix];
                float v00 = Fb[(size_t)ylo * HW + xlo];
                float v01 = Fb[(size_t)ylo * HW + xhi];
                float v10 = Fb[(size_t)yhi * HW + xlo];
                float v11 = Fb[(size_t)yhi * HW + xhi];
                acc += (1.f - fy) * ((1.f - fx) * v00 + fx * v01)
                     + fy * ((1.f - fx) * v10 + fx * v11);
            }
        }
        xpool[obase + px * 256] = f2bf(acc * 0.25f);
    }
}

// ---------------------------------------------------------------------------
// 64x64 bf16 MFMA GEMM, double-buffered, atomic split-K (FC2/head only).
__global__ __launch_bounds__(256) void gemm_bf16_k(const unsigned short* __restrict__ A,
                                                   const unsigned short* __restrict__ W,
                                                   float* __restrict__ Cacc,
                                                   int M, int N, int K, int kchunk) {
    __shared__ __align__(16) unsigned short As[2][8][64][8];
    __shared__ __align__(16) unsigned short Ws[2][8][64][8];

    int t = threadIdx.x;
    int lane = t & 63, wid = t >> 6;
    int m0 = blockIdx.y * 64, n0 = blockIdx.x * 64;
    int k0 = blockIdx.z * kchunk;
    int wm = (wid >> 1) * 32, wn = (wid & 1) * 32;
    int fr = lane & 15, kg = lane >> 4;
    int nsteps = kchunk >> 6;

    f32x4 acc[2][2] = {};

    const unsigned short* Arow = A + (size_t)(m0 + lane) * K;
    const unsigned short* Wrow = W + (size_t)(n0 + lane) * K;

    auto stage = [&](int buf, int kb) {
#pragma unroll
        for (int i = 0; i < 2; i++) {
            int c = wid * 2 + i;
            __builtin_amdgcn_global_load_lds(
                (const __attribute__((address_space(1))) void*)(Arow + kb + c * 8),
                (__attribute__((address_space(3))) void*)(&As[buf][c][0][0]), 16, 0, 0);
            __builtin_amdgcn_global_load_lds(
                (const __attribute__((address_space(1))) void*)(Wrow + kb + c * 8),
                (__attribute__((address_space(3))) void*)(&Ws[buf][c][0][0]), 16, 0, 0);
        }
    };

    stage(0, k0);
    __syncthreads();
    int cur = 0;
    for (int tt = 0; tt < nsteps; ++tt) {
        if (tt + 1 < nsteps) stage(cur ^ 1, k0 + (tt + 1) * 64);
#pragma unroll
        for (int h = 0; h < 2; h++) {
            bf16x8 a0 = *(const bf16x8*)(&As[cur][h * 4 + kg][wm + fr][0]);
            bf16x8 a1 = *(const bf16x8*)(&As[cur][h * 4 + kg][wm + 16 + fr][0]);
            bf16x8 b0 = *(const bf16x8*)(&Ws[cur][h * 4 + kg][wn + fr][0]);
            bf16x8 b1 = *(const bf16x8*)(&Ws[cur][h * 4 + kg][wn + 16 + fr][0]);
            acc[0][0] = __builtin_amdgcn_mfma_f32_16x16x32_bf16(a0, b0, acc[0][0], 0, 0, 0);
            acc[0][1] = __builtin_amdgcn_mfma_f32_16x16x32_bf16(a0, b1, acc[0][1], 0, 0, 0);
            acc[1][0] = __builtin_amdgcn_mfma_f32_16x16x32_bf16(a1, b0, acc[1][0], 0, 0, 0);
            acc[1][1] = __builtin_amdgcn_mfma_f32_16x16x32_bf16(a1, b1, acc[1][1], 0, 0, 0);
        }
        __syncthreads();
        cur ^= 1;
    }

    int row = m0 + wm + (lane >> 4) * 4;
    int col = n0 + wn + fr;
#pragma unroll
    for (int fm = 0; fm < 2; fm++)
#pragma unroll
        for (int fn = 0; fn < 2; fn++)
#pragma unroll
            for (int r = 0; r < 4; r++)
                atomicAdd(&Cacc[(size_t)(row + fm * 16 + r) * N + col + fn * 16],
                          acc[fm][fn][r]);
}

// ---------------------------------------------------------------------------
// 128x128 bf16 MFMA GEMM (FC1), dbuf, split-K PARTIALS (no atomics),
// z-innermost XCD grouping for A/B panel L2 locality. grid = 448 blocks.
__global__ __launch_bounds__(256) void gemm128_bf16_k(const unsigned short* __restrict__ A,
                                                      const unsigned short* __restrict__ W,
                                                      float* __restrict__ Cp,
                                                      int M, int N, int K, int kchunk) {
    __shared__ __align__(16) unsigned short As[2][8][128][8];   // 2 x 16 KB
    __shared__ __align__(16) unsigned short Ws[2][8][128][8];

    int lin  = blockIdx.x;
    int nb   = (lin & 7) * 56 + (lin >> 3);   // 448 = 8 XCD x 56, bijective
    int tile = nb / 14, bz = nb - tile * 14;  // z innermost per tile
    int bx = tile & 7, by = tile >> 3;

    int t = threadIdx.x;
    int lane = t & 63, wid = t >> 6;
    int m0 = by * 128, n0 = bx * 128;
    int k0 = bz * kchunk;
    int wm = (wid >> 1) * 64, wn = (wid & 1) * 64;
    int fr = lane & 15, kg = lane >> 4;
    int nsteps = kchunk >> 6;

    f32x4 acc[4][4] = {};

    auto stage = [&](int buf, int kb) {
#pragma unroll
        for (int i = 0; i < 4; i++) {
            int c   = wid * 4 + i;
            int kgc = c >> 1;
            int r0w = (c & 1) * 64;
            __builtin_amdgcn_global_load_lds(
                (const __attribute__((address_space(1))) void*)
                    (A + (size_t)(m0 + r0w + lane) * K + kb + kgc * 8),
                (__attribute__((address_space(3))) void*)(&As[buf][kgc][r0w][0]), 16, 0, 0);
            __builtin_amdgcn_global_load_lds(
                (const __attribute__((address_space(1))) void*)
                    (W + (size_t)(n0 + r0w + lane) * K + kb + kgc * 8),
                (__attribute__((address_space(3))) void*)(&Ws[buf][kgc][r0w][0]), 16, 0, 0);
        }
    };

    stage(0, k0);
    __syncthreads();
    int cur = 0;
    for (int tt = 0; tt < nsteps; ++tt) {
        if (tt + 1 < nsteps) stage(cur ^ 1, k0 + (tt + 1) * 64);
#pragma unroll
        for (int h = 0; h < 2; h++) {
            bf16x8 av[4], bv[4];
#pragma unroll
            for (int f = 0; f < 4; f++) {
                av[f] = *(const bf16x8*)(&As[cur][h * 4 + kg][wm + f * 16 + fr][0]);
                bv[f] = *(const bf16x8*)(&Ws[cur][h * 4 + kg][wn + f * 16 + fr][0]);
            }
#pragma unroll
            for (int fm = 0; fm < 4; fm++)
#pragma unroll
                for (int fn = 0; fn < 4; fn++)
                    acc[fm][fn] = __builtin_amdgcn_mfma_f32_16x16x32_bf16(
                        av[fm], bv[fn], acc[fm][fn], 0, 0, 0);
        }
        __syncthreads();
        cur ^= 1;
    }

    float* Cout = Cp + (size_t)bz * ((size_t)M * N);
    int row = m0 + wm + (lane >> 4) * 4;
    int col = n0 + wn + fr;
#pragma unroll
    for (int fm = 0; fm < 4; fm++)
#pragma unroll
        for (int fn = 0; fn < 4; fn++)
#pragma unroll
            for (int r = 0; r < 4; r++)
                Cout[(size_t)(row + fm * 16 + r) * N + col + fn * 16] = acc[fm][fn][r];
}

// ---------------------------------------------------------------------------
// sum ks partial slices + bias + relu -> bf16  (N == HIDN)
__global__ __launch_bounds__(256) void fc_ep_k(const float* __restrict__ Cp,
                                               const float* __restrict__ bias,
                                               unsigned short* __restrict__ dst,
                                               int MN, int ks) {
    int i = blockIdx.x * 256 + threadIdx.x;
    if (i >= MN) return;
    float s = 0.f;
    for (int p = 0; p < ks; p++) s += Cp[(size_t)p * MN + i];
    s = fmaxf(s + bias[i & (HIDN - 1)], 0.f);
    dst[i] = f2bf(s);
}

// head accumulator (512x512) -> bias + reg out + softmax(cls) out. Block = roi.
__global__ void head_ep_k(const float* __restrict__ hf,
                          const float* __restrict__ bc,
                          const float* __restrict__ br,
                          float* __restrict__ out) {
    int r = blockIdx.x, l = threadIdx.x;   // 64 threads
    const float* row = hf + (size_t)r * NHEAD;

    float* reg = out + OUT_ROIS + OUT_CLS + (size_t)r * NREG;
    for (int j = l; j < NREG; j += 64) reg[j] = row[NCLS + j] + br[j];

    float v0 = row[l] + bc[l];
    float v1 = (l + 64 < NCLS) ? row[l + 64] + bc[l + 64] : -INFINITY;
    float m = fmaxf(v0, v1);
#pragma unroll
    for (int o = 32; o; o >>= 1) m = fmaxf(m, __shfl_xor(m, o));
    float e0 = __expf(v0 - m);
    float e1 = (l + 64 < NCLS) ? __expf(v1 - m) : 0.f;
    float s = e0 + e1;
#pragma unroll
    for (int o = 32; o; o >>= 1) s += __shfl_xor(s, o);
    float inv = 1.f / s;
    float* cls = out + OUT_ROIS + (size_t)r * NCLS;
    cls[l] = e0 * inv;
    if (l + 64 < NCLS) cls[l + 64] = e1 * inv;
}

// ---------------------------------------------------------------------------
extern "C" void kernel_launch(void* const* d_in, const int* in_sizes, int n_in,
                              void* d_out, int out_size, void* d_ws, size_t ws_size,
                              hipStream_t stream) {
    const float* p2   = (const float*)d_in[0];
    const float* p3   = (const float*)d_in[1];
    const float* p4   = (const float*)d_in[2];
    const float* p5   = (const float*)d_in[3];
    const float* rois = (const float*)d_in[4];
    const float* w1   = (const float*)d_in[5];
    const float* b1   = (const float*)d_in[6];
    const float* w2   = (const float*)d_in[7];
    const float* b2   = (const float*)d_in[8];
    const float* wc   = (const float*)d_in[9];
    const float* bc   = (const float*)d_in[10];
    const float* wr   = (const float*)d_in[11];
    const float* br   = (const float*)d_in[12];

    float* out = (float*)d_out;

    const int KS1 = 14;   // FC1 split-K (12544 = 14 * 896)

    // workspace carve-up (256B-aligned chunks)
    char* p = (char*)d_ws;
    auto alloc = [&](size_t bytes) { char* r = p; p += (bytes + 255) & ~(size_t)255; return r; };
    unsigned short* xpool = (unsigned short*)alloc((size_t)NROI * DDIM * 2);    // 12.8 MB
    unsigned short* y1b   = (unsigned short*)alloc((size_t)NROI * HIDN * 2);
    unsigned short* y2b   = (unsigned short*)alloc((size_t)NROI * HIDN * 2);
    unsigned short* w1b   = (unsigned short*)alloc((size_t)HIDN * DDIM * 2);    // 25.7 MB
    unsigned short* w2b   = (unsigned short*)alloc((size_t)HIDN * HIDN * 2);
    unsigned short* whd   = (unsigned short*)alloc((size_t)NHEAD * HIDN * 2);
    float*          accz  = (float*)alloc((size_t)(NROI * HIDN + NROI * NHEAD) * 4); // 3.1 MB
    unsigned short* ft0 = (unsigned short*)alloc((size_t)2 * 40000 * CCH * 2);  // 41 MB
    unsigned short* ft1 = (unsigned short*)alloc((size_t)2 * 10000 * CCH * 2);
    unsigned short* ft2 = (unsigned short*)alloc((size_t)2 * 2500 * CCH * 2);
    unsigned short* ft3 = (unsigned short*)alloc((size_t)2 * 625 * CCH * 2);
    bool nhwc = (size_t)(p - (char*)d_ws) <= ws_size;

    float* y2f = accz;
    float* hf  = accz + (size_t)NROI * HIDN;
    // FC1 partials alias ft0 (features are dead once roi_align has run;
    // gemm128 runs strictly after roi_align on the same stream). 29.4 <= 41 MB.
    float* part = (float*)ft0;

    prep_small_k<<<PS_B3, 256, 0, stream>>>(rois, w2, wc, wr, out, accz, w2b, whd);
    permute_w1_k<<<HIDN, 256, 0, stream>>>(w1, w1b);

    if (nhwc) {
        transpose_k<<<dim3(832, 4, 2), 256, 0, stream>>>(p2, p3, p4, p5,
                                                         ft0, ft1, ft2, ft3);
        roi_align_k<<<dim3(POOLP, NROI), 256, 0, stream>>>(ft0, ft1, ft2, ft3, rois, xpool);
    } else {
        roi_align_nchw_k<<<dim3(POOLP, NROI), 256, 0, stream>>>(p2, p3, p4, p5, rois, xpool);
    }

    // FC1: (512,12544)x(1024,12544)^T, 128^2 tile, split-K 14 partials
    gemm128_bf16_k<<<8 * 4 * KS1, 256, 0, stream>>>(
        xpool, w1b, part, NROI, HIDN, DDIM, DDIM / KS1);
    fc_ep_k<<<(NROI * HIDN + 255) / 256, 256, 0, stream>>>(part, b1, y1b, NROI * HIDN, KS1);

    // FC2: (512,1024)x(1024,1024)^T, split-K 2, atomic acc
    gemm_bf16_k<<<dim3(HIDN / 64, NROI / 64, 2), 256, 0, stream>>>(
        y1b, w2b, y2f, NROI, HIDN, HIDN, HIDN / 2);
    fc_ep_k<<<(NROI * HIDN + 255) / 256, 256, 0, stream>>>(y2f, b2, y2b, NROI * HIDN, 1);

    // head: (512,1024)x(512,1024)^T, split-K 4, atomic acc
    gemm_bf16_k<<<dim3(NHEAD / 64, NROI / 64, 4), 256, 0, stream>>>(
        y2b, whd, hf, NROI, NHEAD, HIDN, HIDN / 4);
    head_ep_k<<<NROI, 64, 0, stream>>>(hf, bc, br, out);
}